// Round 6
// baseline (89.164 us; speedup 1.0000x reference)
//
#include <hip/hip_runtime.h>

typedef __bf16 bf16x8 __attribute__((ext_vector_type(8)));
typedef __bf16 bf16x4 __attribute__((ext_vector_type(4)));
typedef float  f32x4  __attribute__((ext_vector_type(4)));

#define GLD_LDS16(gsrc, ldst) \
  __builtin_amdgcn_global_load_lds((const __attribute__((address_space(1))) void*)(gsrc), \
                                   (__attribute__((address_space(3))) void*)(ldst), 16, 0, 0)

// ---------------- 1) GroupNorm partial sums ----------------
__global__ __launch_bounds__(256) void gn_partial_k(const float* __restrict__ x,
                                                    float* __restrict__ partial) {
  __shared__ float red[2][4];
  const int t = threadIdx.x;
  const float4* base = (const float4*)(x + (size_t)blockIdx.x * 4096);
  float s = 0.f, sq = 0.f;
#pragma unroll
  for (int kk = 0; kk < 4; ++kk) {
    float4 v = base[t + kk * 256];
    s  += (v.x + v.y) + (v.z + v.w);
    sq += (v.x * v.x + v.y * v.y) + (v.z * v.z + v.w * v.w);
  }
#pragma unroll
  for (int o = 32; o >= 1; o >>= 1) {
    s  += __shfl_down(s, o, 64);
    sq += __shfl_down(sq, o, 64);
  }
  if ((t & 63) == 0) { red[0][t >> 6] = s; red[1][t >> 6] = sq; }
  __syncthreads();
  if (t == 0) {
    float S  = (red[0][0] + red[0][1]) + (red[0][2] + red[0][3]);
    float SQ = (red[1][0] + red[1][1]) + (red[1][2] + red[1][3]);
    partial[blockIdx.x * 2]     = S;
    partial[blockIdx.x * 2 + 1] = SQ;
  }
}

// ---------------- 2) finalize mean/rstd ----------------
__global__ void gn_final_k(const float* __restrict__ partial, float* __restrict__ stats) {
  const int t = threadIdx.x;
  if (t < 32) {
    float S = 0.f, SQ = 0.f;
#pragma unroll
    for (int i = 0; i < 8; ++i) {
      S  += partial[(t * 8 + i) * 2];
      SQ += partial[(t * 8 + i) * 2 + 1];
    }
    float mean = S * (1.f / 32768.f);
    float var  = SQ * (1.f / 32768.f) - mean * mean;
    stats[t * 2]     = mean;
    stats[t * 2 + 1] = rsqrtf(fmaxf(var, 0.f) + 1e-5f);
  }
}

// ---------------- 3) fused GroupNorm-normalize + QKV 1x1 conv ----------------
__global__ __launch_bounds__(192) void qkv_k(const float* __restrict__ x,
                                             const float* __restrict__ stats,
                                             const float* __restrict__ gamma,
                                             const float* __restrict__ beta,
                                             const float* __restrict__ w_qkv,
                                             const float* __restrict__ b_qkv,
                                             __bf16* __restrict__ qo,
                                             __bf16* __restrict__ ko,
                                             __bf16* __restrict__ vto) {
  __shared__ float xn_lds[32 * 68];
  __shared__ float v_lds[64 * 33];
  const int t  = threadIdx.x;
  const int b  = blockIdx.x >> 7;
  const int s0 = (blockIdx.x & 127) * 32;

  for (int idx = t; idx < 2048; idx += 192) {
    int c = idx >> 5, px = idx & 31;
    float v  = x[((size_t)(b * 64 + c)) * 4096 + s0 + px];
    int   g2 = (b * 8 + (c >> 3)) * 2;
    xn_lds[px * 68 + c] = (v - stats[g2]) * stats[g2 + 1] * gamma[c] + beta[c];
  }
  float4 wr[16];
  const float4* wrow = (const float4*)(w_qkv + t * 64);
#pragma unroll
  for (int i = 0; i < 16; ++i) wr[i] = wrow[i];
  const float bias = b_qkv[t];
  __syncthreads();

  for (int px = 0; px < 32; ++px) {
    const float4* xr = (const float4*)&xn_lds[px * 68];
    float a0 = bias, a1 = 0.f, a2 = 0.f, a3 = 0.f;
#pragma unroll
    for (int i = 0; i < 16; i += 4) {
      float4 x0 = xr[i], x1 = xr[i + 1], x2 = xr[i + 2], x3 = xr[i + 3];
      a0 += wr[i    ].x * x0.x + wr[i    ].y * x0.y + wr[i    ].z * x0.z + wr[i    ].w * x0.w;
      a1 += wr[i + 1].x * x1.x + wr[i + 1].y * x1.y + wr[i + 1].z * x1.z + wr[i + 1].w * x1.w;
      a2 += wr[i + 2].x * x2.x + wr[i + 2].y * x2.y + wr[i + 2].z * x2.z + wr[i + 2].w * x2.w;
      a3 += wr[i + 3].x * x3.x + wr[i + 3].y * x3.y + wr[i + 3].z * x3.z + wr[i + 3].w * x3.w;
    }
    float acc = (a0 + a1) + (a2 + a3);
    if (t < 64)
      qo[((size_t)b * 4096 + s0 + px) * 64 + t] = (__bf16)(acc * 0.125f);
    else if (t < 128)
      ko[((size_t)b * 4096 + s0 + px) * 64 + (t - 64)] = (__bf16)acc;
    else
      v_lds[(t - 128) * 33 + px] = acc;
  }
  __syncthreads();
  for (int u = t; u < 2048; u += 192) {
    int rowc = u >> 5, px = u & 31;
    vto[((size_t)(b * 64 + rowc)) * 4096 + s0 + px] = (__bf16)v_lds[rowc * 33 + px];
  }
}

// ---------------- 4) flash attention: SEG=4, single resident generation ----------------
// 512 blocks x 256 threads (4 waves) = exactly 2 blocks/CU, zero dispatch tail.
// Block = (batch, seg of 1024 keys, 128 q-rows); wave = 32 q-rows; 16 K-tiles of 64.
// K/V triple-buffered; stage(kt+2) issued at top of compute(kt); steady-state
// s_waitcnt vmcnt(8) keeps 2 tiles in flight across barriers (T3/T4). Raw s_barrier.
__global__ __launch_bounds__(256, 2) void attn_k(const __bf16* __restrict__ q,
                                                 const __bf16* __restrict__ k,
                                                 const __bf16* __restrict__ vt,
                                                 __bf16* __restrict__ opart,
                                                 float* __restrict__ mlpart) {
  __shared__ __bf16 k_lds[3][4096];   // 64 keys x 64 d, swizzled slots (8KB each)
  __shared__ __bf16 v_lds[3][4096];   // 64 d x 64 keys, swizzled slots
  __shared__ __bf16 p_lds[4][2048];   // per-wave P^T 32 x 64, swizzled (4KB each)
  const int tid  = threadIdx.x;
  const int lane = tid & 63, w = tid >> 6;
  const int row  = lane & 15, grp = lane >> 4;

  // XCD-aware decode: batch pinned to an XCD pair.
  const int blk  = blockIdx.x;
  const int xcd  = blk & 7;
  const int b    = xcd >> 1;
  const int rest = blk >> 3;                        // 0..63
  const int seg  = rest >> 4;                       // 0..3
  const int qblk = (rest & 15) | ((xcd & 1) << 4);  // 0..31
  const int q0   = qblk * 128 + w * 32;             // this wave's 32 q-rows
  const int j0b  = seg * 1024;

  const __bf16* qp = q  + (size_t)b * 4096 * 64;
  const __bf16* kp = k  + (size_t)b * 4096 * 64;
  const __bf16* vp = vt + (size_t)b * 64 * 4096;

  bf16x8 qf[2][2];
#pragma unroll
  for (int rt = 0; rt < 2; ++rt)
#pragma unroll
    for (int kc = 0; kc < 2; ++kc)
      qf[rt][kc] = *(const bf16x8*)(qp + (size_t)(q0 + rt * 16 + row) * 64 + kc * 32 + grp * 8);
  __builtin_amdgcn_sched_barrier(0);   // pin qf loads before staging (vmcnt ledger)

  f32x4 acc[2][4];
#pragma unroll
  for (int rt = 0; rt < 2; ++rt)
#pragma unroll
    for (int dt = 0; dt < 4; ++dt) acc[rt][dt] = (f32x4){0.f, 0.f, 0.f, 0.f};
  float m[2] = {-1e30f, -1e30f}, l[2] = {0.f, 0.f};

  // staging offsets (constant per thread): 2 x 4KB rounds per 8KB tile
  const int soff0 = tid * 16, soff1 = tid * 16 + 4096;
  const int sj0 = soff0 >> 7, sj1 = soff1 >> 7;
  const int sc0 = ((soff0 >> 4) & 7) ^ (sj0 & 7);
  const int sc1 = ((soff1 >> 4) & 7) ^ (sj1 & 7);

  auto stage = [&](int buf, int j0) {
    GLD_LDS16(kp + (size_t)(j0 + sj0) * 64 + sc0 * 8, (char*)(&k_lds[buf][0]) + soff0);
    GLD_LDS16(kp + (size_t)(j0 + sj1) * 64 + sc1 * 8, (char*)(&k_lds[buf][0]) + soff1);
    GLD_LDS16(vp + (size_t)sj0 * 4096 + j0 + sc0 * 8, (char*)(&v_lds[buf][0]) + soff0);
    GLD_LDS16(vp + (size_t)sj1 * 4096 + j0 + sc1 * 8, (char*)(&v_lds[buf][0]) + soff1);
  };

  stage(0, j0b);
  stage(1, j0b + 64);

  char* const pbase = (char*)&p_lds[w][0];
  const int swz = (row & 7) << 3;

#pragma unroll
  for (int kt = 0; kt < 16; ++kt) {
    const int cur = kt % 3;
    if (kt < 14) stage((kt + 2) % 3, j0b + (kt + 2) * 64);   // 2-deep prefetch

    // wait for tile kt only; later tiles stay in flight (counted vmcnt, T4).
    // Ledger: 16 outstanding after prologue (qf 8 + 2 stages); each iter adds 4.
    if (kt < 14)       asm volatile("s_waitcnt vmcnt(8)" ::: "memory");
    else if (kt == 14) asm volatile("s_waitcnt vmcnt(4)" ::: "memory");
    else               asm volatile("s_waitcnt vmcnt(0)" ::: "memory");
    __builtin_amdgcn_s_barrier();   // all waves' tile-kt loads landed

    const char* kbase = (const char*)&k_lds[cur][0];
    const char* vbase = (const char*)&v_lds[cur][0];

    // S^T = K · Q^T (scale folded into Q)
    f32x4 sa[2][4];
#pragma unroll
    for (int rt = 0; rt < 2; ++rt)
#pragma unroll
      for (int jt = 0; jt < 4; ++jt) sa[rt][jt] = (f32x4){0.f, 0.f, 0.f, 0.f};
    __builtin_amdgcn_s_setprio(1);
#pragma unroll
    for (int jt = 0; jt < 4; ++jt) {
      const int jr = jt * 16 + row;
      bf16x8 kf0 = *(const bf16x8*)(kbase + jr * 128 + ((grp ^ (row & 7)) << 4));
      bf16x8 kf1 = *(const bf16x8*)(kbase + jr * 128 + (((4 + grp) ^ (row & 7)) << 4));
      sa[0][jt] = __builtin_amdgcn_mfma_f32_16x16x32_bf16(kf0, qf[0][0], sa[0][jt], 0, 0, 0);
      sa[1][jt] = __builtin_amdgcn_mfma_f32_16x16x32_bf16(kf0, qf[1][0], sa[1][jt], 0, 0, 0);
      sa[0][jt] = __builtin_amdgcn_mfma_f32_16x16x32_bf16(kf1, qf[0][1], sa[0][jt], 0, 0, 0);
      sa[1][jt] = __builtin_amdgcn_mfma_f32_16x16x32_bf16(kf1, qf[1][1], sa[1][jt], 0, 0, 0);
    }
    __builtin_amdgcn_s_setprio(0);

    // online softmax (lane owns 16 keys of one q-row per rt)
#pragma unroll
    for (int rt = 0; rt < 2; ++rt) {
      float t0 = fmaxf(fmaxf(sa[rt][0][0], sa[rt][0][1]), fmaxf(sa[rt][0][2], sa[rt][0][3]));
      float t1 = fmaxf(fmaxf(sa[rt][1][0], sa[rt][1][1]), fmaxf(sa[rt][1][2], sa[rt][1][3]));
      float t2 = fmaxf(fmaxf(sa[rt][2][0], sa[rt][2][1]), fmaxf(sa[rt][2][2], sa[rt][2][3]));
      float t3 = fmaxf(fmaxf(sa[rt][3][0], sa[rt][3][1]), fmaxf(sa[rt][3][2], sa[rt][3][3]));
      float tmax = fmaxf(fmaxf(t0, t1), fmaxf(t2, t3));
      tmax = fmaxf(tmax, __shfl_xor(tmax, 16, 64));
      tmax = fmaxf(tmax, __shfl_xor(tmax, 32, 64));
      float mn = fmaxf(m[rt], tmax);
      float sf = __expf(m[rt] - mn);
      m[rt] = mn;
      float ls = 0.f;
#pragma unroll
      for (int jt = 0; jt < 4; ++jt) {
        float p0 = __expf(sa[rt][jt][0] - mn);
        float p1 = __expf(sa[rt][jt][1] - mn);
        float p2 = __expf(sa[rt][jt][2] - mn);
        float p3 = __expf(sa[rt][jt][3] - mn);
        ls += (p0 + p1) + (p2 + p3);
        bf16x4 pv = {(__bf16)p0, (__bf16)p1, (__bf16)p2, (__bf16)p3};
        *(bf16x4*)(pbase + ((rt * 16 + row) << 7) + ((((grp << 2) + (jt << 4)) ^ swz) << 1)) = pv;
      }
      l[rt] = l[rt] * sf + ls;
#pragma unroll
      for (int dt = 0; dt < 4; ++dt) {
        acc[rt][dt][0] *= sf; acc[rt][dt][1] *= sf;
        acc[rt][dt][2] *= sf; acc[rt][dt][3] *= sf;
      }
    }
    asm volatile("s_waitcnt lgkmcnt(0)" ::: "memory");  // own-wave P visibility

    // O^T += V^T · P^T
    __builtin_amdgcn_s_setprio(1);
#pragma unroll
    for (int kc = 0; kc < 2; ++kc) {
      const int koff = (((kc << 5) + (grp << 3)) ^ swz) << 1;
      bf16x8 af0 = *(const bf16x8*)(pbase + (row << 7) + koff);
      bf16x8 af1 = *(const bf16x8*)(pbase + ((16 + row) << 7) + koff);
#pragma unroll
      for (int dt = 0; dt < 4; ++dt) {
        const int dr = dt * 16 + row;
        bf16x8 vf = *(const bf16x8*)(vbase + dr * 128 + ((((kc << 2) + grp) ^ (row & 7)) << 4));
        acc[0][dt] = __builtin_amdgcn_mfma_f32_16x16x32_bf16(vf, af0, acc[0][dt], 0, 0, 0);
        acc[1][dt] = __builtin_amdgcn_mfma_f32_16x16x32_bf16(vf, af1, acc[1][dt], 0, 0, 0);
      }
    }
    __builtin_amdgcn_s_setprio(0);

    if (kt < 15) __builtin_amdgcn_s_barrier();  // all waves done reading tile kt's buffer
  }

  // epilogue: un-normalized O^T (bf16) + (m, l) for split-K combine
#pragma unroll
  for (int rt = 0; rt < 2; ++rt) {
    float lt = l[rt];
    lt += __shfl_xor(lt, 16, 64);
    lt += __shfl_xor(lt, 32, 64);
    const int qrow = q0 + rt * 16 + row;
    __bf16* ob = opart + ((size_t)(b * 4 + seg) * 4096 + qrow) * 64;
#pragma unroll
    for (int dt = 0; dt < 4; ++dt) {
      bf16x4 ov = {(__bf16)acc[rt][dt][0], (__bf16)acc[rt][dt][1],
                   (__bf16)acc[rt][dt][2], (__bf16)acc[rt][dt][3]};
      *(bf16x4*)(ob + dt * 16 + grp * 4) = ov;
    }
    if (grp == 0) {
      float2 mlv; mlv.x = m[rt]; mlv.y = lt;
      *(float2*)(mlpart + ((size_t)(b * 4 + seg) * 4096 + qrow) * 2) = mlv;
    }
  }
}

// ---------------- 5) split-K combine (4 segs) + proj 1x1 conv + residual ----------------
__global__ __launch_bounds__(256) void proj_k(const __bf16* __restrict__ opart,
                                              const float* __restrict__ mlpart,
                                              const float* __restrict__ x,
                                              const float* __restrict__ w_proj,
                                              const float* __restrict__ b_proj,
                                              float* __restrict__ out) {
  __shared__ float wseg[4][32];
  __shared__ float a_lds[32 * 68];
  __shared__ float o_lds[64 * 33];
  const int t  = threadIdx.x;
  const int b  = blockIdx.x >> 7;
  const int s0 = (blockIdx.x & 127) * 32;

  if (t < 32) {
    const int rowg = s0 + t;
    float ms[4], ls[4], es[4];
    float M = -1e30f;
#pragma unroll
    for (int s = 0; s < 4; ++s) {
      float2 ml = *(const float2*)(mlpart + ((size_t)(b * 4 + s) * 4096 + rowg) * 2);
      ms[s] = ml.x; ls[s] = ml.y;
      M = fmaxf(M, ms[s]);
    }
    float L = 0.f;
#pragma unroll
    for (int s = 0; s < 4; ++s) { es[s] = __expf(ms[s] - M); L += es[s] * ls[s]; }
    float invL = 1.f / L;
#pragma unroll
    for (int s = 0; s < 4; ++s) wseg[s][t] = es[s] * invL;
  }
  __syncthreads();

  for (int i = t; i < 512; i += 256) {
    const int px = i >> 4, c4 = i & 15;
    const __bf16* obase = opart + ((size_t)(b * 4) * 4096 + s0 + px) * 64 + c4 * 4;
    float4 a = {0.f, 0.f, 0.f, 0.f};
#pragma unroll
    for (int s = 0; s < 4; ++s) {
      bf16x4 v = *(const bf16x4*)(obase + (size_t)s * 4096 * 64);
      float wv = wseg[s][px];
      a.x += wv * (float)v[0]; a.y += wv * (float)v[1];
      a.z += wv * (float)v[2]; a.w += wv * (float)v[3];
    }
    *(float4*)(&a_lds[px * 68 + c4 * 4]) = a;
  }

  const int o = t & 63, wg = t >> 6;
  float4 wr[16];
  const float4* wrow = (const float4*)(w_proj + o * 64);
#pragma unroll
  for (int i = 0; i < 16; ++i) wr[i] = wrow[i];
  const float bias = b_proj[o];
  __syncthreads();

  for (int pp = 0; pp < 8; ++pp) {
    const int px = wg * 8 + pp;
    const float4* ar = (const float4*)&a_lds[px * 68];
    float a0 = bias, a1 = 0.f, a2 = 0.f, a3 = 0.f;
#pragma unroll
    for (int i = 0; i < 16; i += 4) {
      float4 x0 = ar[i], x1 = ar[i + 1], x2 = ar[i + 2], x3 = ar[i + 3];
      a0 += wr[i    ].x * x0.x + wr[i    ].y * x0.y + wr[i    ].z * x0.z + wr[i    ].w * x0.w;
      a1 += wr[i + 1].x * x1.x + wr[i + 1].y * x1.y + wr[i + 1].z * x1.z + wr[i + 1].w * x1.w;
      a2 += wr[i + 2].x * x2.x + wr[i + 2].y * x2.y + wr[i + 2].z * x2.z + wr[i + 2].w * x2.w;
      a3 += wr[i + 3].x * x3.x + wr[i + 3].y * x3.y + wr[i + 3].z * x3.z + wr[i + 3].w * x3.w;
    }
    o_lds[o * 33 + px] = (a0 + a1) + (a2 + a3);
  }
  __syncthreads();
  for (int idx = t; idx < 2048; idx += 256) {
    const int c = idx >> 5, px = idx & 31;
    const size_t gi = ((size_t)(b * 64 + c)) * 4096 + s0 + px;
    out[gi] = o_lds[c * 33 + px] + x[gi];
  }
}

// ---------------- launch ----------------
extern "C" void kernel_launch(void* const* d_in, const int* in_sizes, int n_in,
                              void* d_out, int out_size, void* d_ws, size_t ws_size,
                              hipStream_t stream) {
  const float* x      = (const float*)d_in[0];
  const float* gamma  = (const float*)d_in[1];
  const float* beta   = (const float*)d_in[2];
  const float* w_qkv  = (const float*)d_in[3];
  const float* b_qkv  = (const float*)d_in[4];
  const float* w_proj = (const float*)d_in[5];
  const float* b_proj = (const float*)d_in[6];
  float* out = (float*)d_out;

  char* ws = (char*)d_ws;
  float*  partial = (float*)ws;                          // 512 f32
  float*  stats   = partial + 512;                       // 64 f32
  __bf16* qb  = (__bf16*)(ws + 4096);                    // 2MB
  __bf16* kb  = qb  + (size_t)4 * 4096 * 64;             // 2MB
  __bf16* vtb = kb  + (size_t)4 * 4096 * 64;             // 2MB
  __bf16* opart = vtb + (size_t)4 * 4096 * 64;           // 4*4*4096*64 bf16 = 8MB
  float*  mlpart = (float*)(opart + (size_t)4 * 4 * 4096 * 64);  // 0.5MB

  gn_partial_k<<<256, 256, 0, stream>>>(x, partial);
  gn_final_k<<<1, 64, 0, stream>>>(partial, stats);
  qkv_k<<<512, 192, 0, stream>>>(x, stats, gamma, beta, w_qkv, b_qkv, qb, kb, vtb);
  attn_k<<<512, 256, 0, stream>>>(qb, kb, vtb, opart, mlpart);
  proj_k<<<512, 256, 0, stream>>>(opart, mlpart, x, w_proj, b_proj, out);
}

// Round 7
// 89.021 us; speedup vs baseline: 1.0016x; 1.0016x over previous
//
#include <hip/hip_runtime.h>

typedef __bf16 bf16x8 __attribute__((ext_vector_type(8)));
typedef __bf16 bf16x4 __attribute__((ext_vector_type(4)));
typedef float  f32x4  __attribute__((ext_vector_type(4)));

#define GLD_LDS16(gsrc, ldst) \
  __builtin_amdgcn_global_load_lds((const __attribute__((address_space(1))) void*)(gsrc), \
                                   (__attribute__((address_space(3))) void*)(ldst), 16, 0, 0)

// ---------------- 1) GroupNorm partial sums ----------------
__global__ __launch_bounds__(256) void gn_partial_k(const float* __restrict__ x,
                                                    float* __restrict__ partial) {
  __shared__ float red[2][4];
  const int t = threadIdx.x;
  const float4* base = (const float4*)(x + (size_t)blockIdx.x * 4096);
  float s = 0.f, sq = 0.f;
#pragma unroll
  for (int kk = 0; kk < 4; ++kk) {
    float4 v = base[t + kk * 256];
    s  += (v.x + v.y) + (v.z + v.w);
    sq += (v.x * v.x + v.y * v.y) + (v.z * v.z + v.w * v.w);
  }
#pragma unroll
  for (int o = 32; o >= 1; o >>= 1) {
    s  += __shfl_down(s, o, 64);
    sq += __shfl_down(sq, o, 64);
  }
  if ((t & 63) == 0) { red[0][t >> 6] = s; red[1][t >> 6] = sq; }
  __syncthreads();
  if (t == 0) {
    float S  = (red[0][0] + red[0][1]) + (red[0][2] + red[0][3]);
    float SQ = (red[1][0] + red[1][1]) + (red[1][2] + red[1][3]);
    partial[blockIdx.x * 2]     = S;
    partial[blockIdx.x * 2 + 1] = SQ;
  }
}

// ---------------- 2) finalize mean/rstd ----------------
__global__ void gn_final_k(const float* __restrict__ partial, float* __restrict__ stats) {
  const int t = threadIdx.x;
  if (t < 32) {
    float S = 0.f, SQ = 0.f;
#pragma unroll
    for (int i = 0; i < 8; ++i) {
      S  += partial[(t * 8 + i) * 2];
      SQ += partial[(t * 8 + i) * 2 + 1];
    }
    float mean = S * (1.f / 32768.f);
    float var  = SQ * (1.f / 32768.f) - mean * mean;
    stats[t * 2]     = mean;
    stats[t * 2 + 1] = rsqrtf(fmaxf(var, 0.f) + 1e-5f);
  }
}

// ---------------- 3) fused GroupNorm-normalize + QKV 1x1 conv ----------------
__global__ __launch_bounds__(192) void qkv_k(const float* __restrict__ x,
                                             const float* __restrict__ stats,
                                             const float* __restrict__ gamma,
                                             const float* __restrict__ beta,
                                             const float* __restrict__ w_qkv,
                                             const float* __restrict__ b_qkv,
                                             __bf16* __restrict__ qo,
                                             __bf16* __restrict__ ko,
                                             __bf16* __restrict__ vto) {
  __shared__ float xn_lds[32 * 68];
  __shared__ float v_lds[64 * 33];
  const int t  = threadIdx.x;
  const int b  = blockIdx.x >> 7;
  const int s0 = (blockIdx.x & 127) * 32;

  for (int idx = t; idx < 2048; idx += 192) {
    int c = idx >> 5, px = idx & 31;
    float v  = x[((size_t)(b * 64 + c)) * 4096 + s0 + px];
    int   g2 = (b * 8 + (c >> 3)) * 2;
    xn_lds[px * 68 + c] = (v - stats[g2]) * stats[g2 + 1] * gamma[c] + beta[c];
  }
  float4 wr[16];
  const float4* wrow = (const float4*)(w_qkv + t * 64);
#pragma unroll
  for (int i = 0; i < 16; ++i) wr[i] = wrow[i];
  const float bias = b_qkv[t];
  __syncthreads();

  for (int px = 0; px < 32; ++px) {
    const float4* xr = (const float4*)&xn_lds[px * 68];
    float a0 = bias, a1 = 0.f, a2 = 0.f, a3 = 0.f;
#pragma unroll
    for (int i = 0; i < 16; i += 4) {
      float4 x0 = xr[i], x1 = xr[i + 1], x2 = xr[i + 2], x3 = xr[i + 3];
      a0 += wr[i    ].x * x0.x + wr[i    ].y * x0.y + wr[i    ].z * x0.z + wr[i    ].w * x0.w;
      a1 += wr[i + 1].x * x1.x + wr[i + 1].y * x1.y + wr[i + 1].z * x1.z + wr[i + 1].w * x1.w;
      a2 += wr[i + 2].x * x2.x + wr[i + 2].y * x2.y + wr[i + 2].z * x2.z + wr[i + 2].w * x2.w;
      a3 += wr[i + 3].x * x3.x + wr[i + 3].y * x3.y + wr[i + 3].z * x3.z + wr[i + 3].w * x3.w;
    }
    float acc = (a0 + a1) + (a2 + a3);
    if (t < 64)
      qo[((size_t)b * 4096 + s0 + px) * 64 + t] = (__bf16)(acc * 0.125f);
    else if (t < 128)
      ko[((size_t)b * 4096 + s0 + px) * 64 + (t - 64)] = (__bf16)acc;
    else
      v_lds[(t - 128) * 33 + px] = acc;
  }
  __syncthreads();
  for (int u = t; u < 2048; u += 192) {
    int rowc = u >> 5, px = u & 31;
    vto[((size_t)(b * 64 + rowc)) * 4096 + s0 + px] = (__bf16)v_lds[rowc * 33 + px];
  }
}

// ---------------- 4) flash attention: 8-wave blocks, 16 waves/CU, 2-deep pipeline ----------------
// 512 blocks x 512 threads (8 waves) = 2 blocks/CU -> 16 waves/CU (2x round-6 occupancy).
// Block = (batch, seg of 512 keys, 256 q-rows); wave = 32 q-rows; 8 K-tiles of 64.
// K/V triple-buffered (80KB LDS, still 2 blocks/CU); stage(kt+2) at top of compute(kt);
// counted vmcnt: steady vmcnt(4), tail vmcnt(2)/vmcnt(0). Ledger: qf(4) + 2/stage.
__global__ __launch_bounds__(512, 4) void attn_k(const __bf16* __restrict__ q,
                                                 const __bf16* __restrict__ k,
                                                 const __bf16* __restrict__ vt,
                                                 __bf16* __restrict__ opart,
                                                 float* __restrict__ mlpart) {
  __shared__ __bf16 k_lds[3][4096];   // 64 keys x 64 d, swizzled slots (8KB each)
  __shared__ __bf16 v_lds[3][4096];   // 64 d x 64 keys, swizzled slots
  __shared__ __bf16 p_lds[8][2048];   // per-wave P^T 32 x 64, swizzled (4KB each)
  const int tid  = threadIdx.x;
  const int lane = tid & 63, w = tid >> 6;
  const int row  = lane & 15, grp = lane >> 4;

  // XCD-aware decode: batch pinned to an XCD pair.
  const int blk  = blockIdx.x;
  const int xcd  = blk & 7;
  const int b    = xcd >> 1;
  const int rest = blk >> 3;                       // 0..63
  const int seg  = rest >> 3;                      // 0..7
  const int qblk = (rest & 7) | ((xcd & 1) << 3);  // 0..15
  const int q0   = qblk * 256 + w * 32;            // this wave's 32 q-rows
  const int j0b  = seg * 512;

  const __bf16* qp = q  + (size_t)b * 4096 * 64;
  const __bf16* kp = k  + (size_t)b * 4096 * 64;
  const __bf16* vp = vt + (size_t)b * 64 * 4096;

  bf16x8 qf[2][2];
#pragma unroll
  for (int rt = 0; rt < 2; ++rt)
#pragma unroll
    for (int kc = 0; kc < 2; ++kc)
      qf[rt][kc] = *(const bf16x8*)(qp + (size_t)(q0 + rt * 16 + row) * 64 + kc * 32 + grp * 8);
  __builtin_amdgcn_sched_barrier(0);   // pin qf loads before staging (vmcnt ledger)

  f32x4 acc[2][4];
#pragma unroll
  for (int rt = 0; rt < 2; ++rt)
#pragma unroll
    for (int dt = 0; dt < 4; ++dt) acc[rt][dt] = (f32x4){0.f, 0.f, 0.f, 0.f};
  float m[2] = {-1e30f, -1e30f}, l[2] = {0.f, 0.f};

  // staging offsets: 512 threads x 16B = one 8KB tile per round (1 GLD each for K and V)
  const int soff = tid * 16;
  const int sj = soff >> 7;                       // key row 0..63
  const int sc = ((soff >> 4) & 7) ^ (sj & 7);    // pre-swizzled chunk

  auto stage = [&](int buf, int j0) {
    GLD_LDS16(kp + (size_t)(j0 + sj) * 64 + sc * 8, (char*)(&k_lds[buf][0]) + soff);
    GLD_LDS16(vp + (size_t)sj * 4096 + j0 + sc * 8, (char*)(&v_lds[buf][0]) + soff);
  };

  stage(0, j0b);
  stage(1, j0b + 64);

  char* const pbase = (char*)&p_lds[w][0];
  const int swz = (row & 7) << 3;

#pragma unroll
  for (int kt = 0; kt < 8; ++kt) {
    const int cur = kt % 3;
    if (kt < 6) stage((kt + 2) % 3, j0b + (kt + 2) * 64);   // 2-deep prefetch

    // wait for tile kt only; later tiles stay in flight (counted vmcnt, T4).
    // Ledger: kt=0: qf4+s0_2+s1_2+s2_2=10 -> vmcnt(4) drains qf+s0.
    //         kt=1..5: s_kt2+s_kt+1_2+s_kt+2_2=6 -> vmcnt(4) drains s_kt.
    //         kt=6: s6+s7=4 -> vmcnt(2). kt=7: vmcnt(0).
    if (kt < 6)       asm volatile("s_waitcnt vmcnt(4)" ::: "memory");
    else if (kt == 6) asm volatile("s_waitcnt vmcnt(2)" ::: "memory");
    else              asm volatile("s_waitcnt vmcnt(0)" ::: "memory");
    __builtin_amdgcn_s_barrier();   // all waves' tile-kt loads landed

    const char* kbase = (const char*)&k_lds[cur][0];
    const char* vbase = (const char*)&v_lds[cur][0];

    // S^T = K · Q^T (scale folded into Q)
    f32x4 sa[2][4];
#pragma unroll
    for (int rt = 0; rt < 2; ++rt)
#pragma unroll
      for (int jt = 0; jt < 4; ++jt) sa[rt][jt] = (f32x4){0.f, 0.f, 0.f, 0.f};
    __builtin_amdgcn_s_setprio(1);
#pragma unroll
    for (int jt = 0; jt < 4; ++jt) {
      const int jr = jt * 16 + row;
      bf16x8 kf0 = *(const bf16x8*)(kbase + jr * 128 + ((grp ^ (row & 7)) << 4));
      bf16x8 kf1 = *(const bf16x8*)(kbase + jr * 128 + (((4 + grp) ^ (row & 7)) << 4));
      sa[0][jt] = __builtin_amdgcn_mfma_f32_16x16x32_bf16(kf0, qf[0][0], sa[0][jt], 0, 0, 0);
      sa[1][jt] = __builtin_amdgcn_mfma_f32_16x16x32_bf16(kf0, qf[1][0], sa[1][jt], 0, 0, 0);
      sa[0][jt] = __builtin_amdgcn_mfma_f32_16x16x32_bf16(kf1, qf[0][1], sa[0][jt], 0, 0, 0);
      sa[1][jt] = __builtin_amdgcn_mfma_f32_16x16x32_bf16(kf1, qf[1][1], sa[1][jt], 0, 0, 0);
    }
    __builtin_amdgcn_s_setprio(0);

    // online softmax (lane owns 16 keys of one q-row per rt)
#pragma unroll
    for (int rt = 0; rt < 2; ++rt) {
      float t0 = fmaxf(fmaxf(sa[rt][0][0], sa[rt][0][1]), fmaxf(sa[rt][0][2], sa[rt][0][3]));
      float t1 = fmaxf(fmaxf(sa[rt][1][0], sa[rt][1][1]), fmaxf(sa[rt][1][2], sa[rt][1][3]));
      float t2 = fmaxf(fmaxf(sa[rt][2][0], sa[rt][2][1]), fmaxf(sa[rt][2][2], sa[rt][2][3]));
      float t3 = fmaxf(fmaxf(sa[rt][3][0], sa[rt][3][1]), fmaxf(sa[rt][3][2], sa[rt][3][3]));
      float tmax = fmaxf(fmaxf(t0, t1), fmaxf(t2, t3));
      tmax = fmaxf(tmax, __shfl_xor(tmax, 16, 64));
      tmax = fmaxf(tmax, __shfl_xor(tmax, 32, 64));
      float mn = fmaxf(m[rt], tmax);
      float sf = __expf(m[rt] - mn);
      m[rt] = mn;
      float ls = 0.f;
#pragma unroll
      for (int jt = 0; jt < 4; ++jt) {
        float p0 = __expf(sa[rt][jt][0] - mn);
        float p1 = __expf(sa[rt][jt][1] - mn);
        float p2 = __expf(sa[rt][jt][2] - mn);
        float p3 = __expf(sa[rt][jt][3] - mn);
        ls += (p0 + p1) + (p2 + p3);
        bf16x4 pv = {(__bf16)p0, (__bf16)p1, (__bf16)p2, (__bf16)p3};
        *(bf16x4*)(pbase + ((rt * 16 + row) << 7) + ((((grp << 2) + (jt << 4)) ^ swz) << 1)) = pv;
      }
      l[rt] = l[rt] * sf + ls;
#pragma unroll
      for (int dt = 0; dt < 4; ++dt) {
        acc[rt][dt][0] *= sf; acc[rt][dt][1] *= sf;
        acc[rt][dt][2] *= sf; acc[rt][dt][3] *= sf;
      }
    }
    asm volatile("s_waitcnt lgkmcnt(0)" ::: "memory");  // own-wave P visibility

    // O^T += V^T · P^T
    __builtin_amdgcn_s_setprio(1);
#pragma unroll
    for (int kc = 0; kc < 2; ++kc) {
      const int koff = (((kc << 5) + (grp << 3)) ^ swz) << 1;
      bf16x8 af0 = *(const bf16x8*)(pbase + (row << 7) + koff);
      bf16x8 af1 = *(const bf16x8*)(pbase + ((16 + row) << 7) + koff);
#pragma unroll
      for (int dt = 0; dt < 4; ++dt) {
        const int dr = dt * 16 + row;
        bf16x8 vf = *(const bf16x8*)(vbase + dr * 128 + ((((kc << 2) + grp) ^ (row & 7)) << 4));
        acc[0][dt] = __builtin_amdgcn_mfma_f32_16x16x32_bf16(vf, af0, acc[0][dt], 0, 0, 0);
        acc[1][dt] = __builtin_amdgcn_mfma_f32_16x16x32_bf16(vf, af1, acc[1][dt], 0, 0, 0);
      }
    }
    __builtin_amdgcn_s_setprio(0);

    if (kt < 7) __builtin_amdgcn_s_barrier();  // all waves done reading tile kt's buffer
  }

  // epilogue: un-normalized O^T (bf16) + (m, l) for split-K combine
#pragma unroll
  for (int rt = 0; rt < 2; ++rt) {
    float lt = l[rt];
    lt += __shfl_xor(lt, 16, 64);
    lt += __shfl_xor(lt, 32, 64);
    const int qrow = q0 + rt * 16 + row;
    __bf16* ob = opart + ((size_t)(b * 8 + seg) * 4096 + qrow) * 64;
#pragma unroll
    for (int dt = 0; dt < 4; ++dt) {
      bf16x4 ov = {(__bf16)acc[rt][dt][0], (__bf16)acc[rt][dt][1],
                   (__bf16)acc[rt][dt][2], (__bf16)acc[rt][dt][3]};
      *(bf16x4*)(ob + dt * 16 + grp * 4) = ov;
    }
    if (grp == 0) {
      float2 mlv; mlv.x = m[rt]; mlv.y = lt;
      *(float2*)(mlpart + ((size_t)(b * 8 + seg) * 4096 + qrow) * 2) = mlv;
    }
  }
}

// ---------------- 5) split-K combine (8 segs) + proj 1x1 conv + residual ----------------
__global__ __launch_bounds__(256) void proj_k(const __bf16* __restrict__ opart,
                                              const float* __restrict__ mlpart,
                                              const float* __restrict__ x,
                                              const float* __restrict__ w_proj,
                                              const float* __restrict__ b_proj,
                                              float* __restrict__ out) {
  __shared__ float wseg[8][32];
  __shared__ float a_lds[32 * 68];
  __shared__ float o_lds[64 * 33];
  const int t  = threadIdx.x;
  const int b  = blockIdx.x >> 7;
  const int s0 = (blockIdx.x & 127) * 32;

  if (t < 32) {
    const int rowg = s0 + t;
    float ms[8], ls[8], es[8];
    float M = -1e30f;
#pragma unroll
    for (int s = 0; s < 8; ++s) {
      float2 ml = *(const float2*)(mlpart + ((size_t)(b * 8 + s) * 4096 + rowg) * 2);
      ms[s] = ml.x; ls[s] = ml.y;
      M = fmaxf(M, ms[s]);
    }
    float L = 0.f;
#pragma unroll
    for (int s = 0; s < 8; ++s) { es[s] = __expf(ms[s] - M); L += es[s] * ls[s]; }
    float invL = 1.f / L;
#pragma unroll
    for (int s = 0; s < 8; ++s) wseg[s][t] = es[s] * invL;
  }
  __syncthreads();

  for (int i = t; i < 512; i += 256) {
    const int px = i >> 4, c4 = i & 15;
    const __bf16* obase = opart + ((size_t)(b * 8) * 4096 + s0 + px) * 64 + c4 * 4;
    float4 a = {0.f, 0.f, 0.f, 0.f};
#pragma unroll
    for (int s = 0; s < 8; ++s) {
      bf16x4 v = *(const bf16x4*)(obase + (size_t)s * 4096 * 64);
      float wv = wseg[s][px];
      a.x += wv * (float)v[0]; a.y += wv * (float)v[1];
      a.z += wv * (float)v[2]; a.w += wv * (float)v[3];
    }
    *(float4*)(&a_lds[px * 68 + c4 * 4]) = a;
  }

  const int o = t & 63, wg = t >> 6;
  float4 wr[16];
  const float4* wrow = (const float4*)(w_proj + o * 64);
#pragma unroll
  for (int i = 0; i < 16; ++i) wr[i] = wrow[i];
  const float bias = b_proj[o];
  __syncthreads();

  for (int pp = 0; pp < 8; ++pp) {
    const int px = wg * 8 + pp;
    const float4* ar = (const float4*)&a_lds[px * 68];
    float a0 = bias, a1 = 0.f, a2 = 0.f, a3 = 0.f;
#pragma unroll
    for (int i = 0; i < 16; i += 4) {
      float4 x0 = ar[i], x1 = ar[i + 1], x2 = ar[i + 2], x3 = ar[i + 3];
      a0 += wr[i    ].x * x0.x + wr[i    ].y * x0.y + wr[i    ].z * x0.z + wr[i    ].w * x0.w;
      a1 += wr[i + 1].x * x1.x + wr[i + 1].y * x1.y + wr[i + 1].z * x1.z + wr[i + 1].w * x1.w;
      a2 += wr[i + 2].x * x2.x + wr[i + 2].y * x2.y + wr[i + 2].z * x2.z + wr[i + 2].w * x2.w;
      a3 += wr[i + 3].x * x3.x + wr[i + 3].y * x3.y + wr[i + 3].z * x3.z + wr[i + 3].w * x3.w;
    }
    o_lds[o * 33 + px] = (a0 + a1) + (a2 + a3);
  }
  __syncthreads();
  for (int idx = t; idx < 2048; idx += 256) {
    const int c = idx >> 5, px = idx & 31;
    const size_t gi = ((size_t)(b * 64 + c)) * 4096 + s0 + px;
    out[gi] = o_lds[c * 33 + px] + x[gi];
  }
}

// ---------------- launch ----------------
extern "C" void kernel_launch(void* const* d_in, const int* in_sizes, int n_in,
                              void* d_out, int out_size, void* d_ws, size_t ws_size,
                              hipStream_t stream) {
  const float* x      = (const float*)d_in[0];
  const float* gamma  = (const float*)d_in[1];
  const float* beta   = (const float*)d_in[2];
  const float* w_qkv  = (const float*)d_in[3];
  const float* b_qkv  = (const float*)d_in[4];
  const float* w_proj = (const float*)d_in[5];
  const float* b_proj = (const float*)d_in[6];
  float* out = (float*)d_out;

  char* ws = (char*)d_ws;
  float*  partial = (float*)ws;                          // 512 f32
  float*  stats   = partial + 512;                       // 64 f32
  __bf16* qb  = (__bf16*)(ws + 4096);                    // 2MB
  __bf16* kb  = qb  + (size_t)4 * 4096 * 64;             // 2MB
  __bf16* vtb = kb  + (size_t)4 * 4096 * 64;             // 2MB
  __bf16* opart = vtb + (size_t)4 * 4096 * 64;           // 4*8*4096*64 bf16 = 16MB
  float*  mlpart = (float*)(opart + (size_t)4 * 8 * 4096 * 64);  // 1MB

  gn_partial_k<<<256, 256, 0, stream>>>(x, partial);
  gn_final_k<<<1, 64, 0, stream>>>(partial, stats);
  qkv_k<<<512, 192, 0, stream>>>(x, stats, gamma, beta, w_qkv, b_qkv, qb, kb, vtb);
  attn_k<<<512, 512, 0, stream>>>(qb, kb, vtb, opart, mlpart);
  proj_k<<<512, 256, 0, stream>>>(opart, mlpart, x, w_proj, b_proj, out);
}

// Round 8
// 80.377 us; speedup vs baseline: 1.1093x; 1.1075x over previous
//
#include <hip/hip_runtime.h>

typedef __bf16 bf16x8 __attribute__((ext_vector_type(8)));
typedef __bf16 bf16x4 __attribute__((ext_vector_type(4)));
typedef float  f32x4  __attribute__((ext_vector_type(4)));

#define GLD_LDS16(gsrc, ldst) \
  __builtin_amdgcn_global_load_lds((const __attribute__((address_space(1))) void*)(gsrc), \
                                   (__attribute__((address_space(3))) void*)(ldst), 16, 0, 0)

// ---------------- 1) GroupNorm partial sums ----------------
__global__ __launch_bounds__(256) void gn_partial_k(const float* __restrict__ x,
                                                    float* __restrict__ partial) {
  __shared__ float red[2][4];
  const int t = threadIdx.x;
  const float4* base = (const float4*)(x + (size_t)blockIdx.x * 4096);
  float s = 0.f, sq = 0.f;
#pragma unroll
  for (int kk = 0; kk < 4; ++kk) {
    float4 v = base[t + kk * 256];
    s  += (v.x + v.y) + (v.z + v.w);
    sq += (v.x * v.x + v.y * v.y) + (v.z * v.z + v.w * v.w);
  }
#pragma unroll
  for (int o = 32; o >= 1; o >>= 1) {
    s  += __shfl_down(s, o, 64);
    sq += __shfl_down(sq, o, 64);
  }
  if ((t & 63) == 0) { red[0][t >> 6] = s; red[1][t >> 6] = sq; }
  __syncthreads();
  if (t == 0) {
    float S  = (red[0][0] + red[0][1]) + (red[0][2] + red[0][3]);
    float SQ = (red[1][0] + red[1][1]) + (red[1][2] + red[1][3]);
    partial[blockIdx.x * 2]     = S;
    partial[blockIdx.x * 2 + 1] = SQ;
  }
}

// ---------------- 2) finalize mean/rstd ----------------
__global__ void gn_final_k(const float* __restrict__ partial, float* __restrict__ stats) {
  const int t = threadIdx.x;
  if (t < 32) {
    float S = 0.f, SQ = 0.f;
#pragma unroll
    for (int i = 0; i < 8; ++i) {
      S  += partial[(t * 8 + i) * 2];
      SQ += partial[(t * 8 + i) * 2 + 1];
    }
    float mean = S * (1.f / 32768.f);
    float var  = SQ * (1.f / 32768.f) - mean * mean;
    stats[t * 2]     = mean;
    stats[t * 2 + 1] = rsqrtf(fmaxf(var, 0.f) + 1e-5f);
  }
}

// ---------------- 3) fused GroupNorm-normalize + QKV 1x1 conv ----------------
__global__ __launch_bounds__(192) void qkv_k(const float* __restrict__ x,
                                             const float* __restrict__ stats,
                                             const float* __restrict__ gamma,
                                             const float* __restrict__ beta,
                                             const float* __restrict__ w_qkv,
                                             const float* __restrict__ b_qkv,
                                             __bf16* __restrict__ qo,
                                             __bf16* __restrict__ ko,
                                             __bf16* __restrict__ vto) {
  __shared__ float xn_lds[32 * 68];
  __shared__ float v_lds[64 * 33];
  const int t  = threadIdx.x;
  const int b  = blockIdx.x >> 7;
  const int s0 = (blockIdx.x & 127) * 32;

  for (int idx = t; idx < 2048; idx += 192) {
    int c = idx >> 5, px = idx & 31;
    float v  = x[((size_t)(b * 64 + c)) * 4096 + s0 + px];
    int   g2 = (b * 8 + (c >> 3)) * 2;
    xn_lds[px * 68 + c] = (v - stats[g2]) * stats[g2 + 1] * gamma[c] + beta[c];
  }
  float4 wr[16];
  const float4* wrow = (const float4*)(w_qkv + t * 64);
#pragma unroll
  for (int i = 0; i < 16; ++i) wr[i] = wrow[i];
  const float bias = b_qkv[t];
  __syncthreads();

  for (int px = 0; px < 32; ++px) {
    const float4* xr = (const float4*)&xn_lds[px * 68];
    float a0 = bias, a1 = 0.f, a2 = 0.f, a3 = 0.f;
#pragma unroll
    for (int i = 0; i < 16; i += 4) {
      float4 x0 = xr[i], x1 = xr[i + 1], x2 = xr[i + 2], x3 = xr[i + 3];
      a0 += wr[i    ].x * x0.x + wr[i    ].y * x0.y + wr[i    ].z * x0.z + wr[i    ].w * x0.w;
      a1 += wr[i + 1].x * x1.x + wr[i + 1].y * x1.y + wr[i + 1].z * x1.z + wr[i + 1].w * x1.w;
      a2 += wr[i + 2].x * x2.x + wr[i + 2].y * x2.y + wr[i + 2].z * x2.z + wr[i + 2].w * x2.w;
      a3 += wr[i + 3].x * x3.x + wr[i + 3].y * x3.y + wr[i + 3].z * x3.z + wr[i + 3].w * x3.w;
    }
    float acc = (a0 + a1) + (a2 + a3);
    if (t < 64)
      qo[((size_t)b * 4096 + s0 + px) * 64 + t] = (__bf16)(acc * 0.125f);
    else if (t < 128)
      ko[((size_t)b * 4096 + s0 + px) * 64 + (t - 64)] = (__bf16)acc;
    else
      v_lds[(t - 128) * 33 + px] = acc;
  }
  __syncthreads();
  for (int u = t; u < 2048; u += 192) {
    int rowc = u >> 5, px = u & 31;
    vto[((size_t)(b * 64 + rowc)) * 4096 + s0 + px] = (__bf16)v_lds[rowc * 33 + px];
  }
}

// ---------------- 4) flash attention: 8-wave blocks, 16 waves/CU, 2-deep pipeline ----------------
// 512 blocks x 512 threads (8 waves); LDS 80KB -> 2 blocks/CU -> 16 waves/CU.
// __launch_bounds__(512, 2): VGPR cap 256 -> compiler lands ~128 like rounds 5/6 (NO spill;
// round 7's (512,4) forced a 64-VGPR budget and 120MB of scratch writes).
// K/V triple-buffered; stage(kt+2) at top of compute(kt); counted vmcnt (qf4 + 2/stage).
__global__ __launch_bounds__(512, 2) void attn_k(const __bf16* __restrict__ q,
                                                 const __bf16* __restrict__ k,
                                                 const __bf16* __restrict__ vt,
                                                 __bf16* __restrict__ opart,
                                                 float* __restrict__ mlpart) {
  __shared__ __bf16 k_lds[3][4096];   // 64 keys x 64 d, swizzled slots (8KB each)
  __shared__ __bf16 v_lds[3][4096];   // 64 d x 64 keys, swizzled slots
  __shared__ __bf16 p_lds[8][2048];   // per-wave P^T 32 x 64, swizzled (4KB each)
  const int tid  = threadIdx.x;
  const int lane = tid & 63, w = tid >> 6;
  const int row  = lane & 15, grp = lane >> 4;

  // XCD-aware decode: batch pinned to an XCD pair.
  const int blk  = blockIdx.x;
  const int xcd  = blk & 7;
  const int b    = xcd >> 1;
  const int rest = blk >> 3;                       // 0..63
  const int seg  = rest >> 3;                      // 0..7
  const int qblk = (rest & 7) | ((xcd & 1) << 3);  // 0..15
  const int q0   = qblk * 256 + w * 32;            // this wave's 32 q-rows
  const int j0b  = seg * 512;

  const __bf16* qp = q  + (size_t)b * 4096 * 64;
  const __bf16* kp = k  + (size_t)b * 4096 * 64;
  const __bf16* vp = vt + (size_t)b * 64 * 4096;

  bf16x8 qf[2][2];
#pragma unroll
  for (int rt = 0; rt < 2; ++rt)
#pragma unroll
    for (int kc = 0; kc < 2; ++kc)
      qf[rt][kc] = *(const bf16x8*)(qp + (size_t)(q0 + rt * 16 + row) * 64 + kc * 32 + grp * 8);
  __builtin_amdgcn_sched_barrier(0);   // pin qf loads before staging (vmcnt ledger)

  f32x4 acc[2][4];
#pragma unroll
  for (int rt = 0; rt < 2; ++rt)
#pragma unroll
    for (int dt = 0; dt < 4; ++dt) acc[rt][dt] = (f32x4){0.f, 0.f, 0.f, 0.f};
  float m[2] = {-1e30f, -1e30f}, l[2] = {0.f, 0.f};

  // staging offsets: 512 threads x 16B = one 8KB tile per round (1 GLD each for K and V)
  const int soff = tid * 16;
  const int sj = soff >> 7;                       // key row 0..63
  const int sc = ((soff >> 4) & 7) ^ (sj & 7);    // pre-swizzled chunk

  auto stage = [&](int buf, int j0) {
    GLD_LDS16(kp + (size_t)(j0 + sj) * 64 + sc * 8, (char*)(&k_lds[buf][0]) + soff);
    GLD_LDS16(vp + (size_t)sj * 4096 + j0 + sc * 8, (char*)(&v_lds[buf][0]) + soff);
  };

  stage(0, j0b);
  stage(1, j0b + 64);

  char* const pbase = (char*)&p_lds[w][0];
  const int swz = (row & 7) << 3;

#pragma unroll
  for (int kt = 0; kt < 8; ++kt) {
    const int cur = kt % 3;
    if (kt < 6) stage((kt + 2) % 3, j0b + (kt + 2) * 64);   // 2-deep prefetch

    // wait for tile kt only; later tiles stay in flight (counted vmcnt, T4).
    // Ledger: kt=0: qf4+s0_2+s1_2+s2_2=10 -> vmcnt(4) drains qf+s0.
    //         kt=1..5: 6 outstanding -> vmcnt(4) drains s_kt.
    //         kt=6: 4 -> vmcnt(2). kt=7: vmcnt(0).
    if (kt < 6)       asm volatile("s_waitcnt vmcnt(4)" ::: "memory");
    else if (kt == 6) asm volatile("s_waitcnt vmcnt(2)" ::: "memory");
    else              asm volatile("s_waitcnt vmcnt(0)" ::: "memory");
    __builtin_amdgcn_s_barrier();   // all waves' tile-kt loads landed

    const char* kbase = (const char*)&k_lds[cur][0];
    const char* vbase = (const char*)&v_lds[cur][0];

    // S^T = K · Q^T (scale folded into Q)
    f32x4 sa[2][4];
#pragma unroll
    for (int rt = 0; rt < 2; ++rt)
#pragma unroll
      for (int jt = 0; jt < 4; ++jt) sa[rt][jt] = (f32x4){0.f, 0.f, 0.f, 0.f};
    __builtin_amdgcn_s_setprio(1);
#pragma unroll
    for (int jt = 0; jt < 4; ++jt) {
      const int jr = jt * 16 + row;
      bf16x8 kf0 = *(const bf16x8*)(kbase + jr * 128 + ((grp ^ (row & 7)) << 4));
      bf16x8 kf1 = *(const bf16x8*)(kbase + jr * 128 + (((4 + grp) ^ (row & 7)) << 4));
      sa[0][jt] = __builtin_amdgcn_mfma_f32_16x16x32_bf16(kf0, qf[0][0], sa[0][jt], 0, 0, 0);
      sa[1][jt] = __builtin_amdgcn_mfma_f32_16x16x32_bf16(kf0, qf[1][0], sa[1][jt], 0, 0, 0);
      sa[0][jt] = __builtin_amdgcn_mfma_f32_16x16x32_bf16(kf1, qf[0][1], sa[0][jt], 0, 0, 0);
      sa[1][jt] = __builtin_amdgcn_mfma_f32_16x16x32_bf16(kf1, qf[1][1], sa[1][jt], 0, 0, 0);
    }
    __builtin_amdgcn_s_setprio(0);

    // online softmax (lane owns 16 keys of one q-row per rt)
#pragma unroll
    for (int rt = 0; rt < 2; ++rt) {
      float t0 = fmaxf(fmaxf(sa[rt][0][0], sa[rt][0][1]), fmaxf(sa[rt][0][2], sa[rt][0][3]));
      float t1 = fmaxf(fmaxf(sa[rt][1][0], sa[rt][1][1]), fmaxf(sa[rt][1][2], sa[rt][1][3]));
      float t2 = fmaxf(fmaxf(sa[rt][2][0], sa[rt][2][1]), fmaxf(sa[rt][2][2], sa[rt][2][3]));
      float t3 = fmaxf(fmaxf(sa[rt][3][0], sa[rt][3][1]), fmaxf(sa[rt][3][2], sa[rt][3][3]));
      float tmax = fmaxf(fmaxf(t0, t1), fmaxf(t2, t3));
      tmax = fmaxf(tmax, __shfl_xor(tmax, 16, 64));
      tmax = fmaxf(tmax, __shfl_xor(tmax, 32, 64));
      float mn = fmaxf(m[rt], tmax);
      float sf = __expf(m[rt] - mn);
      m[rt] = mn;
      float ls = 0.f;
#pragma unroll
      for (int jt = 0; jt < 4; ++jt) {
        float p0 = __expf(sa[rt][jt][0] - mn);
        float p1 = __expf(sa[rt][jt][1] - mn);
        float p2 = __expf(sa[rt][jt][2] - mn);
        float p3 = __expf(sa[rt][jt][3] - mn);
        ls += (p0 + p1) + (p2 + p3);
        bf16x4 pv = {(__bf16)p0, (__bf16)p1, (__bf16)p2, (__bf16)p3};
        *(bf16x4*)(pbase + ((rt * 16 + row) << 7) + ((((grp << 2) + (jt << 4)) ^ swz) << 1)) = pv;
      }
      l[rt] = l[rt] * sf + ls;
#pragma unroll
      for (int dt = 0; dt < 4; ++dt) {
        acc[rt][dt][0] *= sf; acc[rt][dt][1] *= sf;
        acc[rt][dt][2] *= sf; acc[rt][dt][3] *= sf;
      }
    }
    asm volatile("s_waitcnt lgkmcnt(0)" ::: "memory");  // own-wave P visibility

    // O^T += V^T · P^T
    __builtin_amdgcn_s_setprio(1);
#pragma unroll
    for (int kc = 0; kc < 2; ++kc) {
      const int koff = (((kc << 5) + (grp << 3)) ^ swz) << 1;
      bf16x8 af0 = *(const bf16x8*)(pbase + (row << 7) + koff);
      bf16x8 af1 = *(const bf16x8*)(pbase + ((16 + row) << 7) + koff);
#pragma unroll
      for (int dt = 0; dt < 4; ++dt) {
        const int dr = dt * 16 + row;
        bf16x8 vf = *(const bf16x8*)(vbase + dr * 128 + ((((kc << 2) + grp) ^ (row & 7)) << 4));
        acc[0][dt] = __builtin_amdgcn_mfma_f32_16x16x32_bf16(vf, af0, acc[0][dt], 0, 0, 0);
        acc[1][dt] = __builtin_amdgcn_mfma_f32_16x16x32_bf16(vf, af1, acc[1][dt], 0, 0, 0);
      }
    }
    __builtin_amdgcn_s_setprio(0);

    if (kt < 7) __builtin_amdgcn_s_barrier();  // all waves done reading tile kt's buffer
  }

  // epilogue: un-normalized O^T (bf16) + (m, l) for split-K combine
#pragma unroll
  for (int rt = 0; rt < 2; ++rt) {
    float lt = l[rt];
    lt += __shfl_xor(lt, 16, 64);
    lt += __shfl_xor(lt, 32, 64);
    const int qrow = q0 + rt * 16 + row;
    __bf16* ob = opart + ((size_t)(b * 8 + seg) * 4096 + qrow) * 64;
#pragma unroll
    for (int dt = 0; dt < 4; ++dt) {
      bf16x4 ov = {(__bf16)acc[rt][dt][0], (__bf16)acc[rt][dt][1],
                   (__bf16)acc[rt][dt][2], (__bf16)acc[rt][dt][3]};
      *(bf16x4*)(ob + dt * 16 + grp * 4) = ov;
    }
    if (grp == 0) {
      float2 mlv; mlv.x = m[rt]; mlv.y = lt;
      *(float2*)(mlpart + ((size_t)(b * 8 + seg) * 4096 + qrow) * 2) = mlv;
    }
  }
}

// ---------------- 5) split-K combine (8 segs) + proj 1x1 conv + residual ----------------
__global__ __launch_bounds__(256) void proj_k(const __bf16* __restrict__ opart,
                                              const float* __restrict__ mlpart,
                                              const float* __restrict__ x,
                                              const float* __restrict__ w_proj,
                                              const float* __restrict__ b_proj,
                                              float* __restrict__ out) {
  __shared__ float wseg[8][32];
  __shared__ float a_lds[32 * 68];
  __shared__ float o_lds[64 * 33];
  const int t  = threadIdx.x;
  const int b  = blockIdx.x >> 7;
  const int s0 = (blockIdx.x & 127) * 32;

  if (t < 32) {
    const int rowg = s0 + t;
    float ms[8], ls[8], es[8];
    float M = -1e30f;
#pragma unroll
    for (int s = 0; s < 8; ++s) {
      float2 ml = *(const float2*)(mlpart + ((size_t)(b * 8 + s) * 4096 + rowg) * 2);
      ms[s] = ml.x; ls[s] = ml.y;
      M = fmaxf(M, ms[s]);
    }
    float L = 0.f;
#pragma unroll
    for (int s = 0; s < 8; ++s) { es[s] = __expf(ms[s] - M); L += es[s] * ls[s]; }
    float invL = 1.f / L;
#pragma unroll
    for (int s = 0; s < 8; ++s) wseg[s][t] = es[s] * invL;
  }
  __syncthreads();

  for (int i = t; i < 512; i += 256) {
    const int px = i >> 4, c4 = i & 15;
    const __bf16* obase = opart + ((size_t)(b * 8) * 4096 + s0 + px) * 64 + c4 * 4;
    float4 a = {0.f, 0.f, 0.f, 0.f};
#pragma unroll
    for (int s = 0; s < 8; ++s) {
      bf16x4 v = *(const bf16x4*)(obase + (size_t)s * 4096 * 64);
      float wv = wseg[s][px];
      a.x += wv * (float)v[0]; a.y += wv * (float)v[1];
      a.z += wv * (float)v[2]; a.w += wv * (float)v[3];
    }
    *(float4*)(&a_lds[px * 68 + c4 * 4]) = a;
  }

  const int o = t & 63, wg = t >> 6;
  float4 wr[16];
  const float4* wrow = (const float4*)(w_proj + o * 64);
#pragma unroll
  for (int i = 0; i < 16; ++i) wr[i] = wrow[i];
  const float bias = b_proj[o];
  __syncthreads();

  for (int pp = 0; pp < 8; ++pp) {
    const int px = wg * 8 + pp;
    const float4* ar = (const float4*)&a_lds[px * 68];
    float a0 = bias, a1 = 0.f, a2 = 0.f, a3 = 0.f;
#pragma unroll
    for (int i = 0; i < 16; i += 4) {
      float4 x0 = ar[i], x1 = ar[i + 1], x2 = ar[i + 2], x3 = ar[i + 3];
      a0 += wr[i    ].x * x0.x + wr[i    ].y * x0.y + wr[i    ].z * x0.z + wr[i    ].w * x0.w;
      a1 += wr[i + 1].x * x1.x + wr[i + 1].y * x1.y + wr[i + 1].z * x1.z + wr[i + 1].w * x1.w;
      a2 += wr[i + 2].x * x2.x + wr[i + 2].y * x2.y + wr[i + 2].z * x2.z + wr[i + 2].w * x2.w;
      a3 += wr[i + 3].x * x3.x + wr[i + 3].y * x3.y + wr[i + 3].z * x3.z + wr[i + 3].w * x3.w;
    }
    o_lds[o * 33 + px] = (a0 + a1) + (a2 + a3);
  }
  __syncthreads();
  for (int idx = t; idx < 2048; idx += 256) {
    const int c = idx >> 5, px = idx & 31;
    const size_t gi = ((size_t)(b * 64 + c)) * 4096 + s0 + px;
    out[gi] = o_lds[c * 33 + px] + x[gi];
  }
}

// ---------------- launch ----------------
extern "C" void kernel_launch(void* const* d_in, const int* in_sizes, int n_in,
                              void* d_out, int out_size, void* d_ws, size_t ws_size,
                              hipStream_t stream) {
  const float* x      = (const float*)d_in[0];
  const float* gamma  = (const float*)d_in[1];
  const float* beta   = (const float*)d_in[2];
  const float* w_qkv  = (const float*)d_in[3];
  const float* b_qkv  = (const float*)d_in[4];
  const float* w_proj = (const float*)d_in[5];
  const float* b_proj = (const float*)d_in[6];
  float* out = (float*)d_out;

  char* ws = (char*)d_ws;
  float*  partial = (float*)ws;                          // 512 f32
  float*  stats   = partial + 512;                       // 64 f32
  __bf16* qb  = (__bf16*)(ws + 4096);                    // 2MB
  __bf16* kb  = qb  + (size_t)4 * 4096 * 64;             // 2MB
  __bf16* vtb = kb  + (size_t)4 * 4096 * 64;             // 2MB
  __bf16* opart = vtb + (size_t)4 * 4096 * 64;           // 4*8*4096*64 bf16 = 16MB
  float*  mlpart = (float*)(opart + (size_t)4 * 8 * 4096 * 64);  // 1MB

  gn_partial_k<<<256, 256, 0, stream>>>(x, partial);
  gn_final_k<<<1, 64, 0, stream>>>(partial, stats);
  qkv_k<<<512, 192, 0, stream>>>(x, stats, gamma, beta, w_qkv, b_qkv, qb, kb, vtb);
  attn_k<<<512, 512, 0, stream>>>(qb, kb, vtb, opart, mlpart);
  proj_k<<<512, 256, 0, stream>>>(opart, mlpart, x, w_proj, b_proj, out);
}

// Round 9
// 80.371 us; speedup vs baseline: 1.1094x; 1.0001x over previous
//
#include <hip/hip_runtime.h>

typedef __bf16 bf16x8 __attribute__((ext_vector_type(8)));
typedef __bf16 bf16x4 __attribute__((ext_vector_type(4)));
typedef float  f32x4  __attribute__((ext_vector_type(4)));
typedef float  f32x16 __attribute__((ext_vector_type(16)));

#define GLD_LDS16(gsrc, ldst) \
  __builtin_amdgcn_global_load_lds((const __attribute__((address_space(1))) void*)(gsrc), \
                                   (__attribute__((address_space(3))) void*)(ldst), 16, 0, 0)

__device__ inline unsigned cvt_pk_bf16(float lo, float hi) {
  unsigned r;
  asm("v_cvt_pk_bf16_f32 %0, %1, %2" : "=v"(r) : "v"(lo), "v"(hi));
  return r;
}
__device__ inline void pl32_swap(unsigned& a, unsigned& b) {
  // dst_hi <-> src_lo:  a' = {a_lo, b_lo}, b' = {a_hi, b_hi}
  asm volatile("v_permlane32_swap_b32 %0, %1" : "+v"(a), "+v"(b));
}
__device__ inline f32x16 zero16() {
  f32x16 z;
#pragma unroll
  for (int i = 0; i < 16; ++i) z[i] = 0.f;
  return z;
}

// ---------------- 1) GroupNorm partial sums ----------------
__global__ __launch_bounds__(256) void gn_partial_k(const float* __restrict__ x,
                                                    float* __restrict__ partial) {
  __shared__ float red[2][4];
  const int t = threadIdx.x;
  const float4* base = (const float4*)(x + (size_t)blockIdx.x * 4096);
  float s = 0.f, sq = 0.f;
#pragma unroll
  for (int kk = 0; kk < 4; ++kk) {
    float4 v = base[t + kk * 256];
    s  += (v.x + v.y) + (v.z + v.w);
    sq += (v.x * v.x + v.y * v.y) + (v.z * v.z + v.w * v.w);
  }
#pragma unroll
  for (int o = 32; o >= 1; o >>= 1) {
    s  += __shfl_down(s, o, 64);
    sq += __shfl_down(sq, o, 64);
  }
  if ((t & 63) == 0) { red[0][t >> 6] = s; red[1][t >> 6] = sq; }
  __syncthreads();
  if (t == 0) {
    float S  = (red[0][0] + red[0][1]) + (red[0][2] + red[0][3]);
    float SQ = (red[1][0] + red[1][1]) + (red[1][2] + red[1][3]);
    partial[blockIdx.x * 2]     = S;
    partial[blockIdx.x * 2 + 1] = SQ;
  }
}

// ---------------- 2) finalize mean/rstd ----------------
__global__ void gn_final_k(const float* __restrict__ partial, float* __restrict__ stats) {
  const int t = threadIdx.x;
  if (t < 32) {
    float S = 0.f, SQ = 0.f;
#pragma unroll
    for (int i = 0; i < 8; ++i) {
      S  += partial[(t * 8 + i) * 2];
      SQ += partial[(t * 8 + i) * 2 + 1];
    }
    float mean = S * (1.f / 32768.f);
    float var  = SQ * (1.f / 32768.f) - mean * mean;
    stats[t * 2]     = mean;
    stats[t * 2 + 1] = rsqrtf(fmaxf(var, 0.f) + 1e-5f);
  }
}

// ---------------- 3) fused GroupNorm-normalize + QKV 1x1 conv ----------------
// Q pre-scaled by (1/8)*log2(e): attention runs in exp2 domain.
__global__ __launch_bounds__(192) void qkv_k(const float* __restrict__ x,
                                             const float* __restrict__ stats,
                                             const float* __restrict__ gamma,
                                             const float* __restrict__ beta,
                                             const float* __restrict__ w_qkv,
                                             const float* __restrict__ b_qkv,
                                             __bf16* __restrict__ qo,
                                             __bf16* __restrict__ ko,
                                             __bf16* __restrict__ vto) {
  __shared__ float xn_lds[32 * 68];
  __shared__ float v_lds[64 * 33];
  const int t  = threadIdx.x;
  const int b  = blockIdx.x >> 7;
  const int s0 = (blockIdx.x & 127) * 32;

  for (int idx = t; idx < 2048; idx += 192) {
    int c = idx >> 5, px = idx & 31;
    float v  = x[((size_t)(b * 64 + c)) * 4096 + s0 + px];
    int   g2 = (b * 8 + (c >> 3)) * 2;
    xn_lds[px * 68 + c] = (v - stats[g2]) * stats[g2 + 1] * gamma[c] + beta[c];
  }
  float4 wr[16];
  const float4* wrow = (const float4*)(w_qkv + t * 64);
#pragma unroll
  for (int i = 0; i < 16; ++i) wr[i] = wrow[i];
  const float bias = b_qkv[t];
  __syncthreads();

  for (int px = 0; px < 32; ++px) {
    const float4* xr = (const float4*)&xn_lds[px * 68];
    float a0 = bias, a1 = 0.f, a2 = 0.f, a3 = 0.f;
#pragma unroll
    for (int i = 0; i < 16; i += 4) {
      float4 x0 = xr[i], x1 = xr[i + 1], x2 = xr[i + 2], x3 = xr[i + 3];
      a0 += wr[i    ].x * x0.x + wr[i    ].y * x0.y + wr[i    ].z * x0.z + wr[i    ].w * x0.w;
      a1 += wr[i + 1].x * x1.x + wr[i + 1].y * x1.y + wr[i + 1].z * x1.z + wr[i + 1].w * x1.w;
      a2 += wr[i + 2].x * x2.x + wr[i + 2].y * x2.y + wr[i + 2].z * x2.z + wr[i + 2].w * x2.w;
      a3 += wr[i + 3].x * x3.x + wr[i + 3].y * x3.y + wr[i + 3].z * x3.z + wr[i + 3].w * x3.w;
    }
    float acc = (a0 + a1) + (a2 + a3);
    if (t < 64)
      qo[((size_t)b * 4096 + s0 + px) * 64 + t] = (__bf16)(acc * 0.18033688f);  // 0.125*log2e
    else if (t < 128)
      ko[((size_t)b * 4096 + s0 + px) * 64 + (t - 64)] = (__bf16)acc;
    else
      v_lds[(t - 128) * 33 + px] = acc;
  }
  __syncthreads();
  for (int u = t; u < 2048; u += 192) {
    int rowc = u >> 5, px = u & 31;
    vto[((size_t)(b * 64 + rowc)) * 4096 + s0 + px] = (__bf16)v_lds[rowc * 33 + px];
  }
}

// ---------------- 4) flash attention: 32x32 MFMA, in-register P (cvt_pk + permlane32_swap) ----------------
// 512 blocks x 512 threads (8 waves), 16 waves/CU. Wave = 32 q-rows (one 32-col MFMA tile).
// S^T = mfma32(A=K, B=Q^T): lane(qrow=l&31, h=l>>5) holds 32 of 64 keys for its q-row
//   (key = (reg&3)+8*(reg>>2)+4h+32*tile). Softmax fully in-lane + 1 shfl_xor(32).
// PV: O^T = mfma32(A=V^T, B=P^T); B-frag built IN REGISTERS:
//   chunk c needs P[qrow][16c+8h+i]; i<4 come from the h=0 lane's quad 2(c&1)+h_dest,
//   i>=4 from the h=1 lane's same quad -> v_permlane32_swap(a=w[qd0][j], b=w[qd1][j])
//   yields d_j=a' (own/partner correct per half) and d_{2+j}=b'. 16 cvt_pk + 8 swaps/iter.
// No p_lds, no mid-iter lgkmcnt. Single barrier/iter; stage AFTER barrier into (kt+2)%3
// (== (kt-1)%3, provably drained). vmcnt: kt<7 -> 2, kt=7 -> 0.
__global__ __launch_bounds__(512, 2) void attn_k(const __bf16* __restrict__ q,
                                                 const __bf16* __restrict__ k,
                                                 const __bf16* __restrict__ vt,
                                                 __bf16* __restrict__ opart,
                                                 float* __restrict__ mlpart) {
  __shared__ __bf16 k_lds[3][4096];   // 64 keys x 64 d, swizzled slots (8KB each)
  __shared__ __bf16 v_lds[3][4096];   // 64 d x 64 keys, swizzled slots

  const int tid  = threadIdx.x;
  const int lane = tid & 63, w = tid >> 6;
  const int col  = lane & 31;   // q-row within wave tile; also d-row for V reads
  const int h    = lane >> 5;
  const int swz  = col & 7;

  // XCD-aware decode: batch pinned to an XCD pair.
  const int blk  = blockIdx.x;
  const int xcd  = blk & 7;
  const int b    = xcd >> 1;
  const int rest = blk >> 3;                       // 0..63
  const int seg  = rest >> 3;                      // 0..7
  const int qblk = (rest & 7) | ((xcd & 1) << 3);  // 0..15
  const int q0   = qblk * 256 + w * 32;            // this wave's 32 q-rows
  const int j0b  = seg * 512;

  const __bf16* qp = q  + (size_t)b * 4096 * 64;
  const __bf16* kp = k  + (size_t)b * 4096 * 64;
  const __bf16* vp = vt + (size_t)b * 64 * 4096;

  // Q as B-operand of 32x32x16: lane holds Q[q0+col][16*kk + 8h + i]
  bf16x8 qf[4];
#pragma unroll
  for (int kk = 0; kk < 4; ++kk)
    qf[kk] = *(const bf16x8*)(qp + (size_t)(q0 + col) * 64 + kk * 16 + h * 8);
  __builtin_amdgcn_sched_barrier(0);   // pin qf loads before staging (vmcnt ledger)

  f32x16 acc0 = zero16(), acc1 = zero16();   // d-tiles 0 (d<32), 1 (d>=32)
  float m = -1e30f, l = 0.f;

  // staging: 512 threads x 16B = one full 8KB tile per GLD round
  const int soff = tid * 16;
  const int sj = soff >> 7;                       // row 0..63
  const int sc = ((soff >> 4) & 7) ^ (sj & 7);    // pre-swizzled source chunk

  auto stage = [&](int buf, int j0) {
    GLD_LDS16(kp + (size_t)(j0 + sj) * 64 + sc * 8, (char*)(&k_lds[buf][0]) + soff);
    GLD_LDS16(vp + (size_t)sj * 4096 + j0 + sc * 8, (char*)(&v_lds[buf][0]) + soff);
  };

  stage(0, j0b);
  stage(1, j0b + 64);

#pragma unroll
  for (int kt = 0; kt < 8; ++kt) {
    // Ledger: kt=0: qf(4)+s0(2)+s1(2)=8 -> vmcnt(2) drains qf+s0.
    //         kt=1..6: s_kt(2)+s_{kt+1}(2)=4 -> vmcnt(2) drains s_kt.
    //         kt=7: s7(2) -> vmcnt(0).
    if (kt < 7) asm volatile("s_waitcnt vmcnt(2)" ::: "memory");
    else        asm volatile("s_waitcnt vmcnt(0)" ::: "memory");
    __builtin_amdgcn_s_barrier();   // all waves' tile-kt loads landed; tile kt-1 reads done

    if (kt < 6) stage((kt + 2) % 3, j0b + (kt + 2) * 64);  // writes buf (kt-1)%3: safe

    const char* kbase = (const char*)&k_lds[kt % 3][0];
    const char* vbase = (const char*)&v_lds[kt % 3][0];

    // ---- S^T = K * Q^T (exp2-domain scale folded into Q) ----
    f32x16 sa0 = zero16(), sa1 = zero16();
    __builtin_amdgcn_s_setprio(1);
#pragma unroll
    for (int kk = 0; kk < 4; ++kk) {
      bf16x8 kf0 = *(const bf16x8*)(kbase + col * 128        + (((2 * kk + h) ^ swz) << 4));
      bf16x8 kf1 = *(const bf16x8*)(kbase + (32 + col) * 128 + (((2 * kk + h) ^ swz) << 4));
      sa0 = __builtin_amdgcn_mfma_f32_32x32x16_bf16(kf0, qf[kk], sa0, 0, 0, 0);
      sa1 = __builtin_amdgcn_mfma_f32_32x32x16_bf16(kf1, qf[kk], sa1, 0, 0, 0);
    }
    __builtin_amdgcn_s_setprio(0);

    // ---- online softmax: 32 scores in-lane, one cross-lane max ----
    float x0 = fmaxf(fmaxf(sa0[0], sa0[1]),   fmaxf(sa0[2], sa0[3]));
    float x1 = fmaxf(fmaxf(sa0[4], sa0[5]),   fmaxf(sa0[6], sa0[7]));
    float x2 = fmaxf(fmaxf(sa0[8], sa0[9]),   fmaxf(sa0[10], sa0[11]));
    float x3 = fmaxf(fmaxf(sa0[12], sa0[13]), fmaxf(sa0[14], sa0[15]));
    float y0 = fmaxf(fmaxf(sa1[0], sa1[1]),   fmaxf(sa1[2], sa1[3]));
    float y1 = fmaxf(fmaxf(sa1[4], sa1[5]),   fmaxf(sa1[6], sa1[7]));
    float y2 = fmaxf(fmaxf(sa1[8], sa1[9]),   fmaxf(sa1[10], sa1[11]));
    float y3 = fmaxf(fmaxf(sa1[12], sa1[13]), fmaxf(sa1[14], sa1[15]));
    float mx = fmaxf(fmaxf(fmaxf(x0, x1), fmaxf(x2, x3)),
                     fmaxf(fmaxf(y0, y1), fmaxf(y2, y3)));
    mx = fmaxf(mx, __shfl_xor(mx, 32, 64));
    float mn = fmaxf(m, mx);
    float sf = exp2f(m - mn);
    m = mn;
    float ls = 0.f;
#pragma unroll
    for (int r = 0; r < 16; ++r) { sa0[r] = exp2f(sa0[r] - mn); ls += sa0[r]; }
#pragma unroll
    for (int r = 0; r < 16; ++r) { sa1[r] = exp2f(sa1[r] - mn); ls += sa1[r]; }
    l = l * sf + ls;
    acc0 *= sf;
    acc1 *= sf;

    // ---- pack P to bf16 dwords: w[tile][quad][j] = pk(sa[4qd+2j], sa[4qd+2j+1]) ----
    unsigned w0[8], w1[8];
#pragma unroll
    for (int qd = 0; qd < 4; ++qd) {
      w0[qd * 2]     = cvt_pk_bf16(sa0[4 * qd],     sa0[4 * qd + 1]);
      w0[qd * 2 + 1] = cvt_pk_bf16(sa0[4 * qd + 2], sa0[4 * qd + 3]);
      w1[qd * 2]     = cvt_pk_bf16(sa1[4 * qd],     sa1[4 * qd + 1]);
      w1[qd * 2 + 1] = cvt_pk_bf16(sa1[4 * qd + 2], sa1[4 * qd + 3]);
    }
    // ---- build P^T B-fragments via permlane32_swap ----
    bf16x8 pa[4];
#pragma unroll
    for (int c = 0; c < 4; ++c) {
      const unsigned* wt = (c < 2) ? w0 : w1;
      unsigned a0 = wt[(2 * (c & 1)) * 2],     b0 = wt[(2 * (c & 1) + 1) * 2];
      unsigned a1 = wt[(2 * (c & 1)) * 2 + 1], b1 = wt[(2 * (c & 1) + 1) * 2 + 1];
      pl32_swap(a0, b0);
      pl32_swap(a1, b1);
      uint4 u; u.x = a0; u.y = a1; u.z = b0; u.w = b1;   // d0,d1,d2,d3
      pa[c] = __builtin_bit_cast(bf16x8, u);
    }

    // ---- O^T += V^T * P^T ----
    __builtin_amdgcn_s_setprio(1);
#pragma unroll
    for (int c = 0; c < 4; ++c) {
      bf16x8 vf0 = *(const bf16x8*)(vbase + col * 128        + (((2 * c + h) ^ swz) << 4));
      bf16x8 vf1 = *(const bf16x8*)(vbase + (32 + col) * 128 + (((2 * c + h) ^ swz) << 4));
      acc0 = __builtin_amdgcn_mfma_f32_32x32x16_bf16(vf0, pa[c], acc0, 0, 0, 0);
      acc1 = __builtin_amdgcn_mfma_f32_32x32x16_bf16(vf1, pa[c], acc1, 0, 0, 0);
    }
    __builtin_amdgcn_s_setprio(0);
  }

  // ---- epilogue: un-normalized O^T (bf16) + (m, l) ----
  float lf = l + __shfl_xor(l, 32, 64);
  const int qrow = q0 + col;
  __bf16* ob = opart + ((size_t)(b * 8 + seg) * 4096 + qrow) * 64;
#pragma unroll
  for (int rq = 0; rq < 4; ++rq) {
    const int d0 = 8 * rq + 4 * h;
    bf16x4 o0 = {(__bf16)acc0[4 * rq], (__bf16)acc0[4 * rq + 1],
                 (__bf16)acc0[4 * rq + 2], (__bf16)acc0[4 * rq + 3]};
    bf16x4 o1 = {(__bf16)acc1[4 * rq], (__bf16)acc1[4 * rq + 1],
                 (__bf16)acc1[4 * rq + 2], (__bf16)acc1[4 * rq + 3]};
    *(bf16x4*)(ob + d0)      = o0;
    *(bf16x4*)(ob + 32 + d0) = o1;
  }
  if (h == 0) {
    float2 mlv; mlv.x = m; mlv.y = lf;   // m is in log2 domain
    *(float2*)(mlpart + ((size_t)(b * 8 + seg) * 4096 + qrow) * 2) = mlv;
  }
}

// ---------------- 5) split-K combine (8 segs, exp2 domain) + proj + residual ----------------
__global__ __launch_bounds__(256) void proj_k(const __bf16* __restrict__ opart,
                                              const float* __restrict__ mlpart,
                                              const float* __restrict__ x,
                                              const float* __restrict__ w_proj,
                                              const float* __restrict__ b_proj,
                                              float* __restrict__ out) {
  __shared__ float wseg[8][32];
  __shared__ float a_lds[32 * 68];
  __shared__ float o_lds[64 * 33];
  const int t  = threadIdx.x;
  const int b  = blockIdx.x >> 7;
  const int s0 = (blockIdx.x & 127) * 32;

  if (t < 32) {
    const int rowg = s0 + t;
    float ms[8], ls[8], es[8];
    float M = -1e30f;
#pragma unroll
    for (int s = 0; s < 8; ++s) {
      float2 ml = *(const float2*)(mlpart + ((size_t)(b * 8 + s) * 4096 + rowg) * 2);
      ms[s] = ml.x; ls[s] = ml.y;
      M = fmaxf(M, ms[s]);
    }
    float L = 0.f;
#pragma unroll
    for (int s = 0; s < 8; ++s) { es[s] = exp2f(ms[s] - M); L += es[s] * ls[s]; }
    float invL = 1.f / L;
#pragma unroll
    for (int s = 0; s < 8; ++s) wseg[s][t] = es[s] * invL;
  }
  __syncthreads();

  for (int i = t; i < 512; i += 256) {
    const int px = i >> 4, c4 = i & 15;
    const __bf16* obase = opart + ((size_t)(b * 8) * 4096 + s0 + px) * 64 + c4 * 4;
    float4 a = {0.f, 0.f, 0.f, 0.f};
#pragma unroll
    for (int s = 0; s < 8; ++s) {
      bf16x4 v = *(const bf16x4*)(obase + (size_t)s * 4096 * 64);
      float wv = wseg[s][px];
      a.x += wv * (float)v[0]; a.y += wv * (float)v[1];
      a.z += wv * (float)v[2]; a.w += wv * (float)v[3];
    }
    *(float4*)(&a_lds[px * 68 + c4 * 4]) = a;
  }

  const int o = t & 63, wg = t >> 6;
  float4 wr[16];
  const float4* wrow = (const float4*)(w_proj + o * 64);
#pragma unroll
  for (int i = 0; i < 16; ++i) wr[i] = wrow[i];
  const float bias = b_proj[o];
  __syncthreads();

  for (int pp = 0; pp < 8; ++pp) {
    const int px = wg * 8 + pp;
    const float4* ar = (const float4*)&a_lds[px * 68];
    float a0 = bias, a1 = 0.f, a2 = 0.f, a3 = 0.f;
#pragma unroll
    for (int i = 0; i < 16; i += 4) {
      float4 x0 = ar[i], x1 = ar[i + 1], x2 = ar[i + 2], x3 = ar[i + 3];
      a0 += wr[i    ].x * x0.x + wr[i    ].y * x0.y + wr[i    ].z * x0.z + wr[i    ].w * x0.w;
      a1 += wr[i + 1].x * x1.x + wr[i + 1].y * x1.y + wr[i + 1].z * x1.z + wr[i + 1].w * x1.w;
      a2 += wr[i + 2].x * x2.x + wr[i + 2].y * x2.y + wr[i + 2].z * x2.z + wr[i + 2].w * x2.w;
      a3 += wr[i + 3].x * x3.x + wr[i + 3].y * x3.y + wr[i + 3].z * x3.z + wr[i + 3].w * x3.w;
    }
    o_lds[o * 33 + px] = (a0 + a1) + (a2 + a3);
  }
  __syncthreads();
  for (int idx = t; idx < 2048; idx += 256) {
    const int c = idx >> 5, px = idx & 31;
    const size_t gi = ((size_t)(b * 64 + c)) * 4096 + s0 + px;
    out[gi] = o_lds[c * 33 + px] + x[gi];
  }
}

// ---------------- launch ----------------
extern "C" void kernel_launch(void* const* d_in, const int* in_sizes, int n_in,
                              void* d_out, int out_size, void* d_ws, size_t ws_size,
                              hipStream_t stream) {
  const float* x      = (const float*)d_in[0];
  const float* gamma  = (const float*)d_in[1];
  const float* beta   = (const float*)d_in[2];
  const float* w_qkv  = (const float*)d_in[3];
  const float* b_qkv  = (const float*)d_in[4];
  const float* w_proj = (const float*)d_in[5];
  const float* b_proj = (const float*)d_in[6];
  float* out = (float*)d_out;

  char* ws = (char*)d_ws;
  float*  partial = (float*)ws;                          // 512 f32
  float*  stats   = partial + 512;                       // 64 f32
  __bf16* qb  = (__bf16*)(ws + 4096);                    // 2MB
  __bf16* kb  = qb  + (size_t)4 * 4096 * 64;             // 2MB
  __bf16* vtb = kb  + (size_t)4 * 4096 * 64;             // 2MB
  __bf16* opart = vtb + (size_t)4 * 4096 * 64;           // 16MB (bf16)
  float*  mlpart = (float*)(opart + (size_t)4 * 8 * 4096 * 64);  // 1MB

  gn_partial_k<<<256, 256, 0, stream>>>(x, partial);
  gn_final_k<<<1, 64, 0, stream>>>(partial, stats);
  qkv_k<<<512, 192, 0, stream>>>(x, stats, gamma, beta, w_qkv, b_qkv, qb, kb, vtb);
  attn_k<<<512, 512, 0, stream>>>(qb, kb, vtb, opart, mlpart);
  proj_k<<<512, 256, 0, stream>>>(opart, mlpart, x, w_proj, b_proj, out);
}

// Round 11
// 71.533 us; speedup vs baseline: 1.2465x; 1.1236x over previous
//
#include <hip/hip_runtime.h>

typedef __bf16 bf16x8 __attribute__((ext_vector_type(8)));
typedef __bf16 bf16x4 __attribute__((ext_vector_type(4)));
typedef float  f32x4  __attribute__((ext_vector_type(4)));
typedef float  f32x16 __attribute__((ext_vector_type(16)));

#define GLD_LDS16(gsrc, ldst) \
  __builtin_amdgcn_global_load_lds((const __attribute__((address_space(1))) void*)(gsrc), \
                                   (__attribute__((address_space(3))) void*)(ldst), 16, 0, 0)

__device__ inline unsigned cvt_pk_bf16(float lo, float hi) {
  unsigned r;
  asm("v_cvt_pk_bf16_f32 %0, %1, %2" : "=v"(r) : "v"(lo), "v"(hi));
  return r;
}
__device__ inline void pl32_swap(unsigned& a, unsigned& b) {
  asm volatile("v_permlane32_swap_b32 %0, %1" : "+v"(a), "+v"(b));
}
__device__ inline f32x16 zero16() {
  f32x16 z;
#pragma unroll
  for (int i = 0; i < 16; ++i) z[i] = 0.f;
  return z;
}

// ---------------- 1) GroupNorm partial sums (+ one-time w_qkv hi/lo split) ----------------
__global__ __launch_bounds__(256) void gn_partial_k(const float* __restrict__ x,
                                                    const float* __restrict__ w_qkv,
                                                    float* __restrict__ partial,
                                                    __bf16* __restrict__ whi,
                                                    __bf16* __restrict__ wlo) {
  __shared__ float red[2][4];
  const int t = threadIdx.x;
  // blocks 0..47: also split w_qkv (192x64) into bf16 hi/lo (done once, parallel)
  if (blockIdx.x < 48) {
    const int idx = blockIdx.x * 256 + t;
    float wv = w_qkv[idx];
    __bf16 hh = (__bf16)wv;
    whi[idx] = hh;
    wlo[idx] = (__bf16)(wv - (float)hh);
  }
  const float4* base = (const float4*)(x + (size_t)blockIdx.x * 4096);
  float s = 0.f, sq = 0.f;
#pragma unroll
  for (int kk = 0; kk < 4; ++kk) {
    float4 v = base[t + kk * 256];
    s  += (v.x + v.y) + (v.z + v.w);
    sq += (v.x * v.x + v.y * v.y) + (v.z * v.z + v.w * v.w);
  }
#pragma unroll
  for (int o = 32; o >= 1; o >>= 1) {
    s  += __shfl_down(s, o, 64);
    sq += __shfl_down(sq, o, 64);
  }
  if ((t & 63) == 0) { red[0][t >> 6] = s; red[1][t >> 6] = sq; }
  __syncthreads();
  if (t == 0) {
    float S  = (red[0][0] + red[0][1]) + (red[0][2] + red[0][3]);
    float SQ = (red[1][0] + red[1][1]) + (red[1][2] + red[1][3]);
    partial[blockIdx.x * 2]     = S;
    partial[blockIdx.x * 2 + 1] = SQ;
  }
}

// ---------------- 2) finalize: per-(b,c) scale/shift ----------------
__global__ void gn_final_k(const float* __restrict__ partial,
                           const float* __restrict__ gamma,
                           const float* __restrict__ beta,
                           float* __restrict__ sc) {
  const int t = threadIdx.x;  // 256 = b*64+c
  __shared__ float mu_s[32], rs_s[32];
  if (t < 32) {
    float S = 0.f, SQ = 0.f;
#pragma unroll
    for (int i = 0; i < 8; ++i) {
      S  += partial[(t * 8 + i) * 2];
      SQ += partial[(t * 8 + i) * 2 + 1];
    }
    float mean = S * (1.f / 32768.f);
    float var  = SQ * (1.f / 32768.f) - mean * mean;
    mu_s[t] = mean;
    rs_s[t] = rsqrtf(fmaxf(var, 0.f) + 1e-5f);
  }
  __syncthreads();
  const int b = t >> 6, c = t & 63;
  const int g = b * 8 + (c >> 3);
  float scale = rs_s[g] * gamma[c];
  sc[t * 2]     = scale;
  sc[t * 2 + 1] = beta[c] - mu_s[g] * scale;
}

// ---------------- 3) QKV as split-precision MFMA GEMM (3-term bf16 = ~f32 accuracy) ----------------
// 256 blocks x 256 threads (4 waves); block = (batch, 64 px); wave = 16 px.
// D[o][px] = (w_hi+w_lo)·(xn_hi+xn_lo) ≈ wh·xh + wh·xl + wl·xh  (err ~2^-18 rel).
// B-frags from global x + scale/shift fma, split in-register; A-frags = precomputed whi/wlo.
__global__ __launch_bounds__(256) void qkv_k(const float* __restrict__ x,
                                             const float* __restrict__ sc,
                                             const __bf16* __restrict__ whi,
                                             const __bf16* __restrict__ wlo,
                                             const float* __restrict__ b_qkv,
                                             __bf16* __restrict__ qo,
                                             __bf16* __restrict__ ko,
                                             __bf16* __restrict__ vto) {
  const int tid  = threadIdx.x;
  const int lane = tid & 63, w = tid >> 6;
  const int px16 = lane & 15, grp = lane >> 4;
  const int b    = blockIdx.x >> 6;
  const int s0   = (blockIdx.x & 63) * 64;
  const int pxg  = s0 + w * 16 + px16;

  // ---- B-fragments (hi/lo): xn[c][pxg], c = kk*32 + grp*8 + i ----
  bf16x8 bh[2], bl[2];
#pragma unroll
  for (int kk = 0; kk < 2; ++kk) {
    bf16x8 hv, lv;
#pragma unroll
    for (int i = 0; i < 8; ++i) {
      const int c = kk * 32 + grp * 8 + i;
      float xv = x[((size_t)(b * 64 + c) * 4096) + pxg];
      float2 s = *(const float2*)(sc + (b * 64 + c) * 2);
      float xn = fmaf(xv, s.x, s.y);
      __bf16 hh = (__bf16)xn;
      hv[i] = hh;
      lv[i] = (__bf16)(xn - (float)hh);
    }
    bh[kk] = hv;
    bl[kk] = lv;
  }

  // ---- 12 o-tiles x 2 k-steps x 3 MFMA ----
  f32x4 acc[12];
#pragma unroll
  for (int ot = 0; ot < 12; ++ot) {
    const int o = ot * 16 + px16;
    f32x4 a = {0.f, 0.f, 0.f, 0.f};
#pragma unroll
    for (int kk = 0; kk < 2; ++kk) {
      const size_t wo = (size_t)o * 64 + kk * 32 + grp * 8;
      bf16x8 ah = *(const bf16x8*)(whi + wo);
      bf16x8 al = *(const bf16x8*)(wlo + wo);
      a = __builtin_amdgcn_mfma_f32_16x16x32_bf16(ah, bh[kk], a, 0, 0, 0);
      a = __builtin_amdgcn_mfma_f32_16x16x32_bf16(ah, bl[kk], a, 0, 0, 0);
      a = __builtin_amdgcn_mfma_f32_16x16x32_bf16(al, bh[kk], a, 0, 0, 0);
    }
    acc[ot] = a;
  }

  // ---- stores: D col = px (lane&15), D row = o = ot*16 + grp*4 + r ----
#pragma unroll
  for (int ot = 0; ot < 4; ++ot) {   // Q, pre-scaled 0.125*log2(e)
    const int ob = ot * 16 + grp * 4;
    float4 bias = *(const float4*)(b_qkv + ob);
    f32x4 a = acc[ot];
    bf16x4 qv = {(__bf16)((a[0] + bias.x) * 0.18033688f),
                 (__bf16)((a[1] + bias.y) * 0.18033688f),
                 (__bf16)((a[2] + bias.z) * 0.18033688f),
                 (__bf16)((a[3] + bias.w) * 0.18033688f)};
    *(bf16x4*)(qo + ((size_t)b * 4096 + pxg) * 64 + ob) = qv;
  }
#pragma unroll
  for (int ot = 4; ot < 8; ++ot) {   // K
    const int ob = (ot - 4) * 16 + grp * 4;
    float4 bias = *(const float4*)(b_qkv + 64 + ob);
    f32x4 a = acc[ot];
    bf16x4 kv = {(__bf16)(a[0] + bias.x), (__bf16)(a[1] + bias.y),
                 (__bf16)(a[2] + bias.z), (__bf16)(a[3] + bias.w)};
    *(bf16x4*)(ko + ((size_t)b * 4096 + pxg) * 64 + ob) = kv;
  }
#pragma unroll
  for (int ot = 8; ot < 12; ++ot) {  // V^T
    const int ob = (ot - 8) * 16 + grp * 4;
    float4 bias = *(const float4*)(b_qkv + 128 + ob);
    f32x4 a = acc[ot];
#pragma unroll
    for (int r = 0; r < 4; ++r) {
      float bv = (r == 0) ? bias.x : (r == 1) ? bias.y : (r == 2) ? bias.z : bias.w;
      vto[((size_t)(b * 64 + ob + r)) * 4096 + pxg] = (__bf16)(a[r] + bv);
    }
  }
}

// ---------------- 4) flash attention (round-9 structure, unchanged) ----------------
__global__ __launch_bounds__(512, 2) void attn_k(const __bf16* __restrict__ q,
                                                 const __bf16* __restrict__ k,
                                                 const __bf16* __restrict__ vt,
                                                 __bf16* __restrict__ opart,
                                                 float* __restrict__ mlpart) {
  __shared__ __bf16 k_lds[3][4096];
  __shared__ __bf16 v_lds[3][4096];

  const int tid  = threadIdx.x;
  const int lane = tid & 63, w = tid >> 6;
  const int col  = lane & 31;
  const int h    = lane >> 5;
  const int swz  = col & 7;

  const int blk  = blockIdx.x;
  const int xcd  = blk & 7;
  const int b    = xcd >> 1;
  const int rest = blk >> 3;
  const int seg  = rest >> 3;
  const int qblk = (rest & 7) | ((xcd & 1) << 3);
  const int q0   = qblk * 256 + w * 32;
  const int j0b  = seg * 512;

  const __bf16* qp = q  + (size_t)b * 4096 * 64;
  const __bf16* kp = k  + (size_t)b * 4096 * 64;
  const __bf16* vp = vt + (size_t)b * 64 * 4096;

  bf16x8 qf[4];
#pragma unroll
  for (int kk = 0; kk < 4; ++kk)
    qf[kk] = *(const bf16x8*)(qp + (size_t)(q0 + col) * 64 + kk * 16 + h * 8);
  __builtin_amdgcn_sched_barrier(0);   // pin qf loads before staging (vmcnt ledger)

  f32x16 acc0 = zero16(), acc1 = zero16();
  float m = -1e30f, l = 0.f;

  const int soff = tid * 16;
  const int sj = soff >> 7;
  const int sc2 = ((soff >> 4) & 7) ^ (sj & 7);

  auto stage = [&](int buf, int j0) {
    GLD_LDS16(kp + (size_t)(j0 + sj) * 64 + sc2 * 8, (char*)(&k_lds[buf][0]) + soff);
    GLD_LDS16(vp + (size_t)sj * 4096 + j0 + sc2 * 8, (char*)(&v_lds[buf][0]) + soff);
  };

  stage(0, j0b);
  stage(1, j0b + 64);

#pragma unroll
  for (int kt = 0; kt < 8; ++kt) {
    if (kt < 7) asm volatile("s_waitcnt vmcnt(2)" ::: "memory");
    else        asm volatile("s_waitcnt vmcnt(0)" ::: "memory");
    __builtin_amdgcn_s_barrier();

    if (kt < 6) stage((kt + 2) % 3, j0b + (kt + 2) * 64);

    const char* kbase = (const char*)&k_lds[kt % 3][0];
    const char* vbase = (const char*)&v_lds[kt % 3][0];

    f32x16 sa0 = zero16(), sa1 = zero16();
    __builtin_amdgcn_s_setprio(1);
#pragma unroll
    for (int kk = 0; kk < 4; ++kk) {
      bf16x8 kf0 = *(const bf16x8*)(kbase + col * 128        + (((2 * kk + h) ^ swz) << 4));
      bf16x8 kf1 = *(const bf16x8*)(kbase + (32 + col) * 128 + (((2 * kk + h) ^ swz) << 4));
      sa0 = __builtin_amdgcn_mfma_f32_32x32x16_bf16(kf0, qf[kk], sa0, 0, 0, 0);
      sa1 = __builtin_amdgcn_mfma_f32_32x32x16_bf16(kf1, qf[kk], sa1, 0, 0, 0);
    }
    __builtin_amdgcn_s_setprio(0);

    float x0 = fmaxf(fmaxf(sa0[0], sa0[1]),   fmaxf(sa0[2], sa0[3]));
    float x1 = fmaxf(fmaxf(sa0[4], sa0[5]),   fmaxf(sa0[6], sa0[7]));
    float x2 = fmaxf(fmaxf(sa0[8], sa0[9]),   fmaxf(sa0[10], sa0[11]));
    float x3 = fmaxf(fmaxf(sa0[12], sa0[13]), fmaxf(sa0[14], sa0[15]));
    float y0 = fmaxf(fmaxf(sa1[0], sa1[1]),   fmaxf(sa1[2], sa1[3]));
    float y1 = fmaxf(fmaxf(sa1[4], sa1[5]),   fmaxf(sa1[6], sa1[7]));
    float y2 = fmaxf(fmaxf(sa1[8], sa1[9]),   fmaxf(sa1[10], sa1[11]));
    float y3 = fmaxf(fmaxf(sa1[12], sa1[13]), fmaxf(sa1[14], sa1[15]));
    float mx = fmaxf(fmaxf(fmaxf(x0, x1), fmaxf(x2, x3)),
                     fmaxf(fmaxf(y0, y1), fmaxf(y2, y3)));
    mx = fmaxf(mx, __shfl_xor(mx, 32, 64));
    float mn = fmaxf(m, mx);
    float sf = exp2f(m - mn);
    m = mn;
    float ls = 0.f;
#pragma unroll
    for (int r = 0; r < 16; ++r) { sa0[r] = exp2f(sa0[r] - mn); ls += sa0[r]; }
#pragma unroll
    for (int r = 0; r < 16; ++r) { sa1[r] = exp2f(sa1[r] - mn); ls += sa1[r]; }
    l = l * sf + ls;
    acc0 *= sf;
    acc1 *= sf;

    unsigned w0[8], w1[8];
#pragma unroll
    for (int qd = 0; qd < 4; ++qd) {
      w0[qd * 2]     = cvt_pk_bf16(sa0[4 * qd],     sa0[4 * qd + 1]);
      w0[qd * 2 + 1] = cvt_pk_bf16(sa0[4 * qd + 2], sa0[4 * qd + 3]);
      w1[qd * 2]     = cvt_pk_bf16(sa1[4 * qd],     sa1[4 * qd + 1]);
      w1[qd * 2 + 1] = cvt_pk_bf16(sa1[4 * qd + 2], sa1[4 * qd + 3]);
    }
    bf16x8 pa[4];
#pragma unroll
    for (int c = 0; c < 4; ++c) {
      const unsigned* wt = (c < 2) ? w0 : w1;
      unsigned a0 = wt[(2 * (c & 1)) * 2],     b0 = wt[(2 * (c & 1) + 1) * 2];
      unsigned a1 = wt[(2 * (c & 1)) * 2 + 1], b1 = wt[(2 * (c & 1) + 1) * 2 + 1];
      pl32_swap(a0, b0);
      pl32_swap(a1, b1);
      uint4 u; u.x = a0; u.y = a1; u.z = b0; u.w = b1;
      pa[c] = __builtin_bit_cast(bf16x8, u);
    }

    __builtin_amdgcn_s_setprio(1);
#pragma unroll
    for (int c = 0; c < 4; ++c) {
      bf16x8 vf0 = *(const bf16x8*)(vbase + col * 128        + (((2 * c + h) ^ swz) << 4));
      bf16x8 vf1 = *(const bf16x8*)(vbase + (32 + col) * 128 + (((2 * c + h) ^ swz) << 4));
      acc0 = __builtin_amdgcn_mfma_f32_32x32x16_bf16(vf0, pa[c], acc0, 0, 0, 0);
      acc1 = __builtin_amdgcn_mfma_f32_32x32x16_bf16(vf1, pa[c], acc1, 0, 0, 0);
    }
    __builtin_amdgcn_s_setprio(0);
  }

  float lf = l + __shfl_xor(l, 32, 64);
  const int qrow = q0 + col;
  __bf16* ob = opart + ((size_t)(b * 8 + seg) * 4096 + qrow) * 64;
#pragma unroll
  for (int rq = 0; rq < 4; ++rq) {
    const int d0 = 8 * rq + 4 * h;
    bf16x4 o0 = {(__bf16)acc0[4 * rq], (__bf16)acc0[4 * rq + 1],
                 (__bf16)acc0[4 * rq + 2], (__bf16)acc0[4 * rq + 3]};
    bf16x4 o1 = {(__bf16)acc1[4 * rq], (__bf16)acc1[4 * rq + 1],
                 (__bf16)acc1[4 * rq + 2], (__bf16)acc1[4 * rq + 3]};
    *(bf16x4*)(ob + d0)      = o0;
    *(bf16x4*)(ob + 32 + d0) = o1;
  }
  if (h == 0) {
    float2 mlv; mlv.x = m; mlv.y = lf;   // m in log2 domain
    *(float2*)(mlpart + ((size_t)(b * 8 + seg) * 4096 + qrow) * 2) = mlv;
  }
}

// ---------------- 5) split-K combine (8 segs, exp2 domain) + proj + residual ----------------
__global__ __launch_bounds__(256) void proj_k(const __bf16* __restrict__ opart,
                                              const float* __restrict__ mlpart,
                                              const float* __restrict__ x,
                                              const float* __restrict__ w_proj,
                                              const float* __restrict__ b_proj,
                                              float* __restrict__ out) {
  __shared__ float wseg[8][32];
  __shared__ float a_lds[32 * 68];
  __shared__ float o_lds[64 * 33];
  const int t  = threadIdx.x;
  const int b  = blockIdx.x >> 7;
  const int s0 = (blockIdx.x & 127) * 32;

  if (t < 32) {
    const int rowg = s0 + t;
    float ms[8], ls[8], es[8];
    float M = -1e30f;
#pragma unroll
    for (int s = 0; s < 8; ++s) {
      float2 ml = *(const float2*)(mlpart + ((size_t)(b * 8 + s) * 4096 + rowg) * 2);
      ms[s] = ml.x; ls[s] = ml.y;
      M = fmaxf(M, ms[s]);
    }
    float L = 0.f;
#pragma unroll
    for (int s = 0; s < 8; ++s) { es[s] = exp2f(ms[s] - M); L += es[s] * ls[s]; }
    float invL = 1.f / L;
#pragma unroll
    for (int s = 0; s < 8; ++s) wseg[s][t] = es[s] * invL;
  }
  __syncthreads();

  for (int i = t; i < 512; i += 256) {
    const int px = i >> 4, c4 = i & 15;
    const __bf16* obase = opart + ((size_t)(b * 8) * 4096 + s0 + px) * 64 + c4 * 4;
    float4 a = {0.f, 0.f, 0.f, 0.f};
#pragma unroll
    for (int s = 0; s < 8; ++s) {
      bf16x4 v = *(const bf16x4*)(obase + (size_t)s * 4096 * 64);
      float wv = wseg[s][px];
      a.x += wv * (float)v[0]; a.y += wv * (float)v[1];
      a.z += wv * (float)v[2]; a.w += wv * (float)v[3];
    }
    *(float4*)(&a_lds[px * 68 + c4 * 4]) = a;
  }

  const int o = t & 63, wg = t >> 6;
  float4 wr[16];
  const float4* wrow = (const float4*)(w_proj + o * 64);
#pragma unroll
  for (int i = 0; i < 16; ++i) wr[i] = wrow[i];
  const float bias = b_proj[o];
  __syncthreads();

  for (int pp = 0; pp < 8; ++pp) {
    const int px = wg * 8 + pp;
    const float4* ar = (const float4*)&a_lds[px * 68];
    float a0 = bias, a1 = 0.f, a2 = 0.f, a3 = 0.f;
#pragma unroll
    for (int i = 0; i < 16; i += 4) {
      float4 x0 = ar[i], x1 = ar[i + 1], x2 = ar[i + 2], x3 = ar[i + 3];
      a0 += wr[i    ].x * x0.x + wr[i    ].y * x0.y + wr[i    ].z * x0.z + wr[i    ].w * x0.w;
      a1 += wr[i + 1].x * x1.x + wr[i + 1].y * x1.y + wr[i + 1].z * x1.z + wr[i + 1].w * x1.w;
      a2 += wr[i + 2].x * x2.x + wr[i + 2].y * x2.y + wr[i + 2].z * x2.z + wr[i + 2].w * x2.w;
      a3 += wr[i + 3].x * x3.x + wr[i + 3].y * x3.y + wr[i + 3].z * x3.z + wr[i + 3].w * x3.w;
    }
    o_lds[o * 33 + px] = (a0 + a1) + (a2 + a3);
  }
  __syncthreads();
  for (int idx = t; idx < 2048; idx += 256) {
    const int c = idx >> 5, px = idx & 31;
    const size_t gi = ((size_t)(b * 64 + c)) * 4096 + s0 + px;
    out[gi] = o_lds[c * 33 + px] + x[gi];
  }
}

// ---------------- launch ----------------
extern "C" void kernel_launch(void* const* d_in, const int* in_sizes, int n_in,
                              void* d_out, int out_size, void* d_ws, size_t ws_size,
                              hipStream_t stream) {
  const float* x      = (const float*)d_in[0];
  const float* gamma  = (const float*)d_in[1];
  const float* beta   = (const float*)d_in[2];
  const float* w_qkv  = (const float*)d_in[3];
  const float* b_qkv  = (const float*)d_in[4];
  const float* w_proj = (const float*)d_in[5];
  const float* b_proj = (const float*)d_in[6];
  float* out = (float*)d_out;

  char* ws = (char*)d_ws;
  float*  partial = (float*)ws;                          // 512 f32  @ 0
  float*  scbuf   = partial + 512;                       // 512 f32  @ 2KB
  __bf16* whi     = (__bf16*)(ws + 4096);                // 12288 bf16 = 24KB
  __bf16* wlo     = whi + 12288;                         // 24KB
  __bf16* qb  = (__bf16*)(ws + 65536);                   // 2MB
  __bf16* kb  = qb  + (size_t)4 * 4096 * 64;             // 2MB
  __bf16* vtb = kb  + (size_t)4 * 4096 * 64;             // 2MB
  __bf16* opart = vtb + (size_t)4 * 4096 * 64;           // 16MB (bf16)
  float*  mlpart = (float*)(opart + (size_t)4 * 8 * 4096 * 64);  // 1MB

  gn_partial_k<<<256, 256, 0, stream>>>(x, w_qkv, partial, whi, wlo);
  gn_final_k<<<1, 256, 0, stream>>>(partial, gamma, beta, scbuf);
  qkv_k<<<256, 256, 0, stream>>>(x, scbuf, whi, wlo, b_qkv, qb, kb, vtb);
  attn_k<<<512, 512, 0, stream>>>(qb, kb, vtb, opart, mlpart);
  proj_k<<<512, 256, 0, stream>>>(opart, mlpart, x, w_proj, b_proj, out);
}

// Round 12
// 67.984 us; speedup vs baseline: 1.3115x; 1.0522x over previous
//
#include <hip/hip_runtime.h>

typedef __bf16 bf16x8 __attribute__((ext_vector_type(8)));
typedef __bf16 bf16x4 __attribute__((ext_vector_type(4)));
typedef float  f32x4  __attribute__((ext_vector_type(4)));
typedef float  f32x16 __attribute__((ext_vector_type(16)));

#define GLD_LDS16(gsrc, ldst) \
  __builtin_amdgcn_global_load_lds((const __attribute__((address_space(1))) void*)(gsrc), \
                                   (__attribute__((address_space(3))) void*)(ldst), 16, 0, 0)

__device__ inline unsigned cvt_pk_bf16(float lo, float hi) {
  unsigned r;
  asm("v_cvt_pk_bf16_f32 %0, %1, %2" : "=v"(r) : "v"(lo), "v"(hi));
  return r;
}
__device__ inline void pl32_swap(unsigned& a, unsigned& b) {
  asm volatile("v_permlane32_swap_b32 %0, %1" : "+v"(a), "+v"(b));
}
__device__ inline f32x16 zero16() {
  f32x16 z;
#pragma unroll
  for (int i = 0; i < 16; ++i) z[i] = 0.f;
  return z;
}

// ---------------- 1) GroupNorm partial sums (+ one-time w_qkv hi/lo split) ----------------
__global__ __launch_bounds__(256) void gn_partial_k(const float* __restrict__ x,
                                                    const float* __restrict__ w_qkv,
                                                    float* __restrict__ partial,
                                                    __bf16* __restrict__ whi,
                                                    __bf16* __restrict__ wlo) {
  __shared__ float red[2][4];
  const int t = threadIdx.x;
  if (blockIdx.x < 48) {   // split w_qkv (192x64) into bf16 hi/lo once
    const int idx = blockIdx.x * 256 + t;
    float wv = w_qkv[idx];
    __bf16 hh = (__bf16)wv;
    whi[idx] = hh;
    wlo[idx] = (__bf16)(wv - (float)hh);
  }
  const float4* base = (const float4*)(x + (size_t)blockIdx.x * 4096);
  float s = 0.f, sq = 0.f;
#pragma unroll
  for (int kk = 0; kk < 4; ++kk) {
    float4 v = base[t + kk * 256];
    s  += (v.x + v.y) + (v.z + v.w);
    sq += (v.x * v.x + v.y * v.y) + (v.z * v.z + v.w * v.w);
  }
#pragma unroll
  for (int o = 32; o >= 1; o >>= 1) {
    s  += __shfl_down(s, o, 64);
    sq += __shfl_down(sq, o, 64);
  }
  if ((t & 63) == 0) { red[0][t >> 6] = s; red[1][t >> 6] = sq; }
  __syncthreads();
  if (t == 0) {
    float S  = (red[0][0] + red[0][1]) + (red[0][2] + red[0][3]);
    float SQ = (red[1][0] + red[1][1]) + (red[1][2] + red[1][3]);
    partial[blockIdx.x * 2]     = S;
    partial[blockIdx.x * 2 + 1] = SQ;
  }
}

// ---------------- 2) QKV split-precision MFMA GEMM, gn_final fused in-block ----------------
// 256 blocks x 256 threads (4 waves); block = (batch, 64 px); wave = 16 px.
// Block prologue re-reduces this batch's 64 partial pairs -> per-channel scale/shift in LDS.
__global__ __launch_bounds__(256) void qkv_k(const float* __restrict__ x,
                                             const float* __restrict__ partial,
                                             const float* __restrict__ gamma,
                                             const float* __restrict__ beta,
                                             const __bf16* __restrict__ whi,
                                             const __bf16* __restrict__ wlo,
                                             const float* __restrict__ b_qkv,
                                             __bf16* __restrict__ qo,
                                             __bf16* __restrict__ ko,
                                             __bf16* __restrict__ vto) {
  __shared__ float mu_s[8], rs_s[8], sc_l[128];
  const int tid  = threadIdx.x;
  const int lane = tid & 63, w = tid >> 6;
  const int px16 = lane & 15, grp = lane >> 4;
  const int b    = blockIdx.x >> 6;
  const int s0   = (blockIdx.x & 63) * 64;
  const int pxg  = s0 + w * 16 + px16;

  // fused gn_final: groups of this batch only
  if (tid < 8) {
    float S = 0.f, SQ = 0.f;
#pragma unroll
    for (int i = 0; i < 8; ++i) {
      S  += partial[((b * 8 + tid) * 8 + i) * 2];
      SQ += partial[((b * 8 + tid) * 8 + i) * 2 + 1];
    }
    float mean = S * (1.f / 32768.f);
    float var  = SQ * (1.f / 32768.f) - mean * mean;
    mu_s[tid] = mean;
    rs_s[tid] = rsqrtf(fmaxf(var, 0.f) + 1e-5f);
  }
  __syncthreads();
  if (tid < 64) {
    const int g = tid >> 3;
    float scale = rs_s[g] * gamma[tid];
    sc_l[tid * 2]     = scale;
    sc_l[tid * 2 + 1] = beta[tid] - mu_s[g] * scale;
  }
  __syncthreads();

  // ---- B-fragments (hi/lo): xn[c][pxg], c = kk*32 + grp*8 + i ----
  bf16x8 bh[2], bl[2];
#pragma unroll
  for (int kk = 0; kk < 2; ++kk) {
    bf16x8 hv, lv;
#pragma unroll
    for (int i = 0; i < 8; ++i) {
      const int c = kk * 32 + grp * 8 + i;
      float xv = x[((size_t)(b * 64 + c) * 4096) + pxg];
      float xn = fmaf(xv, sc_l[c * 2], sc_l[c * 2 + 1]);
      __bf16 hh = (__bf16)xn;
      hv[i] = hh;
      lv[i] = (__bf16)(xn - (float)hh);
    }
    bh[kk] = hv;
    bl[kk] = lv;
  }

  // ---- 12 o-tiles x 2 k-steps x 3 MFMA (split precision) ----
  f32x4 acc[12];
#pragma unroll
  for (int ot = 0; ot < 12; ++ot) {
    const int o = ot * 16 + px16;
    f32x4 a = {0.f, 0.f, 0.f, 0.f};
#pragma unroll
    for (int kk = 0; kk < 2; ++kk) {
      const size_t wo = (size_t)o * 64 + kk * 32 + grp * 8;
      bf16x8 ah = *(const bf16x8*)(whi + wo);
      bf16x8 al = *(const bf16x8*)(wlo + wo);
      a = __builtin_amdgcn_mfma_f32_16x16x32_bf16(ah, bh[kk], a, 0, 0, 0);
      a = __builtin_amdgcn_mfma_f32_16x16x32_bf16(ah, bl[kk], a, 0, 0, 0);
      a = __builtin_amdgcn_mfma_f32_16x16x32_bf16(al, bh[kk], a, 0, 0, 0);
    }
    acc[ot] = a;
  }

  // ---- stores ----
#pragma unroll
  for (int ot = 0; ot < 4; ++ot) {   // Q, pre-scaled 0.125*log2(e)
    const int ob = ot * 16 + grp * 4;
    float4 bias = *(const float4*)(b_qkv + ob);
    f32x4 a = acc[ot];
    bf16x4 qv = {(__bf16)((a[0] + bias.x) * 0.18033688f),
                 (__bf16)((a[1] + bias.y) * 0.18033688f),
                 (__bf16)((a[2] + bias.z) * 0.18033688f),
                 (__bf16)((a[3] + bias.w) * 0.18033688f)};
    *(bf16x4*)(qo + ((size_t)b * 4096 + pxg) * 64 + ob) = qv;
  }
#pragma unroll
  for (int ot = 4; ot < 8; ++ot) {   // K
    const int ob = (ot - 4) * 16 + grp * 4;
    float4 bias = *(const float4*)(b_qkv + 64 + ob);
    f32x4 a = acc[ot];
    bf16x4 kv = {(__bf16)(a[0] + bias.x), (__bf16)(a[1] + bias.y),
                 (__bf16)(a[2] + bias.z), (__bf16)(a[3] + bias.w)};
    *(bf16x4*)(ko + ((size_t)b * 4096 + pxg) * 64 + ob) = kv;
  }
#pragma unroll
  for (int ot = 8; ot < 12; ++ot) {  // V^T
    const int ob = (ot - 8) * 16 + grp * 4;
    float4 bias = *(const float4*)(b_qkv + 128 + ob);
    f32x4 a = acc[ot];
#pragma unroll
    for (int r = 0; r < 4; ++r) {
      float bv = (r == 0) ? bias.x : (r == 1) ? bias.y : (r == 2) ? bias.z : bias.w;
      vto[((size_t)(b * 64 + ob + r)) * 4096 + pxg] = (__bf16)(a[r] + bv);
    }
  }
}

// ---------------- 3) flash attention: 4-buffer, 2 tiles per barrier, defer-rescale ----------------
// 512 blocks x 512 threads (8 waves), 16 waves/CU. Wave = 32 q-rows.
// 4 LDS buffer pairs (64KB): tiles t0..t7 map to buf t%4. One barrier per 2 tiles
// (4 barriers total vs 8) -> halves lockstep stalls, doubles per-barrier compute span.
// Ledger: prologue qf(4)+t0..t3(2 each)=12; iter0 vmcnt(4) [drains qf,t0,t1];
// iters1-3 vmcnt(0) on loads issued one full 2-tile span earlier. Stage {t4,t5}/{t6,t7}
// right after iter-1/iter-2 barriers into buffers retired at the preceding barrier.
__global__ __launch_bounds__(512, 2) void attn_k(const __bf16* __restrict__ q,
                                                 const __bf16* __restrict__ k,
                                                 const __bf16* __restrict__ vt,
                                                 __bf16* __restrict__ opart,
                                                 float* __restrict__ mlpart) {
  __shared__ __bf16 k_lds[4][4096];   // 64 keys x 64 d each, swizzled slots (8KB)
  __shared__ __bf16 v_lds[4][4096];   // 64 d x 64 keys each, swizzled slots

  const int tid  = threadIdx.x;
  const int lane = tid & 63, w = tid >> 6;
  const int col  = lane & 31;
  const int h    = lane >> 5;
  const int swz  = col & 7;

  const int blk  = blockIdx.x;
  const int xcd  = blk & 7;
  const int b    = xcd >> 1;
  const int rest = blk >> 3;
  const int seg  = rest >> 3;
  const int qblk = (rest & 7) | ((xcd & 1) << 3);
  const int q0   = qblk * 256 + w * 32;
  const int j0b  = seg * 512;

  const __bf16* qp = q  + (size_t)b * 4096 * 64;
  const __bf16* kp = k  + (size_t)b * 4096 * 64;
  const __bf16* vp = vt + (size_t)b * 64 * 4096;

  bf16x8 qf[4];
#pragma unroll
  for (int kk = 0; kk < 4; ++kk)
    qf[kk] = *(const bf16x8*)(qp + (size_t)(q0 + col) * 64 + kk * 16 + h * 8);
  __builtin_amdgcn_sched_barrier(0);   // pin qf loads before staging (vmcnt ledger)

  f32x16 acc0 = zero16(), acc1 = zero16();
  float m = -1e30f, l = 0.f;

  const int soff = tid * 16;
  const int sj = soff >> 7;
  const int sc2 = ((soff >> 4) & 7) ^ (sj & 7);

  auto stage = [&](int buf, int j0) {
    GLD_LDS16(kp + (size_t)(j0 + sj) * 64 + sc2 * 8, (char*)(&k_lds[buf][0]) + soff);
    GLD_LDS16(vp + (size_t)sj * 4096 + j0 + sc2 * 8, (char*)(&v_lds[buf][0]) + soff);
  };

  stage(0, j0b);
  stage(1, j0b + 64);
  stage(2, j0b + 128);
  stage(3, j0b + 192);

#pragma unroll
  for (int kt = 0; kt < 4; ++kt) {
    // wait for this iteration's TWO tiles (2kt, 2kt+1)
    if (kt == 0) asm volatile("s_waitcnt vmcnt(4)" ::: "memory");
    else         asm volatile("s_waitcnt vmcnt(0)" ::: "memory");
    __builtin_amdgcn_s_barrier();      // loads landed + previous iter's buffers retired

    if (kt == 1) { stage(0, j0b + 256); stage(1, j0b + 320); }  // t4,t5 -> b0,b1
    if (kt == 2) { stage(2, j0b + 384); stage(3, j0b + 448); }  // t6,t7 -> b2,b3

#pragma unroll
    for (int sub = 0; sub < 2; ++sub) {
      const int buf = (2 * kt + sub) & 3;
      const char* kbase = (const char*)&k_lds[buf][0];
      const char* vbase = (const char*)&v_lds[buf][0];

      // ---- S^T = K · Q^T (exp2 domain) ----
      f32x16 sa0 = zero16(), sa1 = zero16();
      __builtin_amdgcn_s_setprio(1);
#pragma unroll
      for (int kk = 0; kk < 4; ++kk) {
        bf16x8 kf0 = *(const bf16x8*)(kbase + col * 128        + (((2 * kk + h) ^ swz) << 4));
        bf16x8 kf1 = *(const bf16x8*)(kbase + (32 + col) * 128 + (((2 * kk + h) ^ swz) << 4));
        sa0 = __builtin_amdgcn_mfma_f32_32x32x16_bf16(kf0, qf[kk], sa0, 0, 0, 0);
        sa1 = __builtin_amdgcn_mfma_f32_32x32x16_bf16(kf1, qf[kk], sa1, 0, 0, 0);
      }
      __builtin_amdgcn_s_setprio(0);

      // ---- online softmax, defer-rescale (T13, THR=8 in log2 units) ----
      float x0 = fmaxf(fmaxf(sa0[0], sa0[1]),   fmaxf(sa0[2], sa0[3]));
      float x1 = fmaxf(fmaxf(sa0[4], sa0[5]),   fmaxf(sa0[6], sa0[7]));
      float x2 = fmaxf(fmaxf(sa0[8], sa0[9]),   fmaxf(sa0[10], sa0[11]));
      float x3 = fmaxf(fmaxf(sa0[12], sa0[13]), fmaxf(sa0[14], sa0[15]));
      float y0 = fmaxf(fmaxf(sa1[0], sa1[1]),   fmaxf(sa1[2], sa1[3]));
      float y1 = fmaxf(fmaxf(sa1[4], sa1[5]),   fmaxf(sa1[6], sa1[7]));
      float y2 = fmaxf(fmaxf(sa1[8], sa1[9]),   fmaxf(sa1[10], sa1[11]));
      float y3 = fmaxf(fmaxf(sa1[12], sa1[13]), fmaxf(sa1[14], sa1[15]));
      float mx = fmaxf(fmaxf(fmaxf(x0, x1), fmaxf(x2, x3)),
                       fmaxf(fmaxf(y0, y1), fmaxf(y2, y3)));
      mx = fmaxf(mx, __shfl_xor(mx, 32, 64));
      if (!__all(mx <= m + 8.f)) {     // rescale only when the running max really grew
        float mn = fmaxf(m, mx);
        float sf = exp2f(m - mn);
        m = mn;
        l *= sf;
        acc0 *= sf;
        acc1 *= sf;
      }
      float ls = 0.f;
#pragma unroll
      for (int r = 0; r < 16; ++r) { sa0[r] = exp2f(sa0[r] - m); ls += sa0[r]; }
#pragma unroll
      for (int r = 0; r < 16; ++r) { sa1[r] = exp2f(sa1[r] - m); ls += sa1[r]; }
      l += ls;

      // ---- pack P to bf16 + permlane32_swap -> B-fragments in registers ----
      unsigned w0[8], w1[8];
#pragma unroll
      for (int qd = 0; qd < 4; ++qd) {
        w0[qd * 2]     = cvt_pk_bf16(sa0[4 * qd],     sa0[4 * qd + 1]);
        w0[qd * 2 + 1] = cvt_pk_bf16(sa0[4 * qd + 2], sa0[4 * qd + 3]);
        w1[qd * 2]     = cvt_pk_bf16(sa1[4 * qd],     sa1[4 * qd + 1]);
        w1[qd * 2 + 1] = cvt_pk_bf16(sa1[4 * qd + 2], sa1[4 * qd + 3]);
      }
      bf16x8 pa[4];
#pragma unroll
      for (int c = 0; c < 4; ++c) {
        const unsigned* wt = (c < 2) ? w0 : w1;
        unsigned a0 = wt[(2 * (c & 1)) * 2],     b0 = wt[(2 * (c & 1) + 1) * 2];
        unsigned a1 = wt[(2 * (c & 1)) * 2 + 1], b1 = wt[(2 * (c & 1) + 1) * 2 + 1];
        pl32_swap(a0, b0);
        pl32_swap(a1, b1);
        uint4 u; u.x = a0; u.y = a1; u.z = b0; u.w = b1;
        pa[c] = __builtin_bit_cast(bf16x8, u);
      }

      // ---- O^T += V^T · P^T ----
      __builtin_amdgcn_s_setprio(1);
#pragma unroll
      for (int c = 0; c < 4; ++c) {
        bf16x8 vf0 = *(const bf16x8*)(vbase + col * 128        + (((2 * c + h) ^ swz) << 4));
        bf16x8 vf1 = *(const bf16x8*)(vbase + (32 + col) * 128 + (((2 * c + h) ^ swz) << 4));
        acc0 = __builtin_amdgcn_mfma_f32_32x32x16_bf16(vf0, pa[c], acc0, 0, 0, 0);
        acc1 = __builtin_amdgcn_mfma_f32_32x32x16_bf16(vf1, pa[c], acc1, 0, 0, 0);
      }
      __builtin_amdgcn_s_setprio(0);
    }
  }

  // ---- epilogue: un-normalized O^T (bf16) + (m, l) ----
  float lf = l + __shfl_xor(l, 32, 64);
  const int qrow = q0 + col;
  __bf16* ob = opart + ((size_t)(b * 8 + seg) * 4096 + qrow) * 64;
#pragma unroll
  for (int rq = 0; rq < 4; ++rq) {
    const int d0 = 8 * rq + 4 * h;
    bf16x4 o0 = {(__bf16)acc0[4 * rq], (__bf16)acc0[4 * rq + 1],
                 (__bf16)acc0[4 * rq + 2], (__bf16)acc0[4 * rq + 3]};
    bf16x4 o1 = {(__bf16)acc1[4 * rq], (__bf16)acc1[4 * rq + 1],
                 (__bf16)acc1[4 * rq + 2], (__bf16)acc1[4 * rq + 3]};
    *(bf16x4*)(ob + d0)      = o0;
    *(bf16x4*)(ob + 32 + d0) = o1;
  }
  if (h == 0) {
    float2 mlv; mlv.x = m; mlv.y = lf;   // m in log2 domain
    *(float2*)(mlpart + ((size_t)(b * 8 + seg) * 4096 + qrow) * 2) = mlv;
  }
}

// ---------------- 4) split-K combine (8 segs, exp2 domain) + proj + residual ----------------
__global__ __launch_bounds__(256) void proj_k(const __bf16* __restrict__ opart,
                                              const float* __restrict__ mlpart,
                                              const float* __restrict__ x,
                                              const float* __restrict__ w_proj,
                                              const float* __restrict__ b_proj,
                                              float* __restrict__ out) {
  __shared__ float wseg[8][32];
  __shared__ float a_lds[32 * 68];
  __shared__ float o_lds[64 * 33];
  const int t  = threadIdx.x;
  const int b  = blockIdx.x >> 7;
  const int s0 = (blockIdx.x & 127) * 32;

  if (t < 32) {
    const int rowg = s0 + t;
    float ms[8], ls[8], es[8];
    float M = -1e30f;
#pragma unroll
    for (int s = 0; s < 8; ++s) {
      float2 ml = *(const float2*)(mlpart + ((size_t)(b * 8 + s) * 4096 + rowg) * 2);
      ms[s] = ml.x; ls[s] = ml.y;
      M = fmaxf(M, ms[s]);
    }
    float L = 0.f;
#pragma unroll
    for (int s = 0; s < 8; ++s) { es[s] = exp2f(ms[s] - M); L += es[s] * ls[s]; }
    float invL = 1.f / L;
#pragma unroll
    for (int s = 0; s < 8; ++s) wseg[s][t] = es[s] * invL;
  }
  __syncthreads();

  for (int i = t; i < 512; i += 256) {
    const int px = i >> 4, c4 = i & 15;
    const __bf16* obase = opart + ((size_t)(b * 8) * 4096 + s0 + px) * 64 + c4 * 4;
    float4 a = {0.f, 0.f, 0.f, 0.f};
#pragma unroll
    for (int s = 0; s < 8; ++s) {
      bf16x4 v = *(const bf16x4*)(obase + (size_t)s * 4096 * 64);
      float wv = wseg[s][px];
      a.x += wv * (float)v[0]; a.y += wv * (float)v[1];
      a.z += wv * (float)v[2]; a.w += wv * (float)v[3];
    }
    *(float4*)(&a_lds[px * 68 + c4 * 4]) = a;
  }

  const int o = t & 63, wg = t >> 6;
  float4 wr[16];
  const float4* wrow = (const float4*)(w_proj + o * 64);
#pragma unroll
  for (int i = 0; i < 16; ++i) wr[i] = wrow[i];
  const float bias = b_proj[o];
  __syncthreads();

  for (int pp = 0; pp < 8; ++pp) {
    const int px = wg * 8 + pp;
    const float4* ar = (const float4*)&a_lds[px * 68];
    float a0 = bias, a1 = 0.f, a2 = 0.f, a3 = 0.f;
#pragma unroll
    for (int i = 0; i < 16; i += 4) {
      float4 x0 = ar[i], x1 = ar[i + 1], x2 = ar[i + 2], x3 = ar[i + 3];
      a0 += wr[i    ].x * x0.x + wr[i    ].y * x0.y + wr[i    ].z * x0.z + wr[i    ].w * x0.w;
      a1 += wr[i + 1].x * x1.x + wr[i + 1].y * x1.y + wr[i + 1].z * x1.z + wr[i + 1].w * x1.w;
      a2 += wr[i + 2].x * x2.x + wr[i + 2].y * x2.y + wr[i + 2].z * x2.z + wr[i + 2].w * x2.w;
      a3 += wr[i + 3].x * x3.x + wr[i + 3].y * x3.y + wr[i + 3].z * x3.z + wr[i + 3].w * x3.w;
    }
    o_lds[o * 33 + px] = (a0 + a1) + (a2 + a3);
  }
  __syncthreads();
  for (int idx = t; idx < 2048; idx += 256) {
    const int c = idx >> 5, px = idx & 31;
    const size_t gi = ((size_t)(b * 64 + c)) * 4096 + s0 + px;
    out[gi] = o_lds[c * 33 + px] + x[gi];
  }
}

// ---------------- launch ----------------
extern "C" void kernel_launch(void* const* d_in, const int* in_sizes, int n_in,
                              void* d_out, int out_size, void* d_ws, size_t ws_size,
                              hipStream_t stream) {
  const float* x      = (const float*)d_in[0];
  const float* gamma  = (const float*)d_in[1];
  const float* beta   = (const float*)d_in[2];
  const float* w_qkv  = (const float*)d_in[3];
  const float* b_qkv  = (const float*)d_in[4];
  const float* w_proj = (const float*)d_in[5];
  const float* b_proj = (const float*)d_in[6];
  float* out = (float*)d_out;

  char* ws = (char*)d_ws;
  float*  partial = (float*)ws;                          // 512 f32  @ 0
  __bf16* whi     = (__bf16*)(ws + 4096);                // 24KB
  __bf16* wlo     = whi + 12288;                         // 24KB
  __bf16* qb  = (__bf16*)(ws + 65536);                   // 2MB
  __bf16* kb  = qb  + (size_t)4 * 4096 * 64;             // 2MB
  __bf16* vtb = kb  + (size_t)4 * 4096 * 64;             // 2MB
  __bf16* opart = vtb + (size_t)4 * 4096 * 64;           // 16MB (bf16)
  float*  mlpart = (float*)(opart + (size_t)4 * 8 * 4096 * 64);  // 1MB

  gn_partial_k<<<256, 256, 0, stream>>>(x, w_qkv, partial, whi, wlo);
  qkv_k<<<256, 256, 0, stream>>>(x, partial, gamma, beta, whi, wlo, b_qkv, qb, kb, vtb);
  attn_k<<<512, 512, 0, stream>>>(qb, kb, vtb, opart, mlpart);
  proj_k<<<512, 256, 0, stream>>>(opart, mlpart, x, w_proj, b_proj, out);
}